// Round 2
// baseline (3328.327 us; speedup 1.0000x reference)
//
#include <hip/hip_runtime.h>
#include <hip/hip_bf16.h>
#include <cmath>
#include <complex>
#include <algorithm>

typedef __hip_bfloat16 bf16;

#define NN 16384

// paths (l1,l2,lo) and flattened w3j offsets; P_G = position of path within its lo-group
constexpr int P_L1[11] = {0,0,0,1,1,1,1,2,2,2,2};
constexpr int P_L2[11] = {0,1,2,0,1,1,2,0,1,2,2};
constexpr int P_LO[11] = {0,1,2,1,0,2,1,2,1,0,2};
constexpr int P_OFF[11]= {0,1,10,35,44,53,98,143,168,213,238}; // sizes 1,9,25,9,9,45,45,25,45,25,125 -> 363
constexpr int P_G[11]  = {0,0,0,1,1,1,2,2,3,2,3};

struct W3JPack { float v[363]; };

// ---------------------------------------------------------------------------
// Generic 128x128-tile f32 GEMM, 256 thr, 8x8 microtile.
// AMODE: 1 = A bf16 row-major [M][K]
//        2 = gated-x: A[R=(n,i)][u] = x[n*1152+xoff+u*SPAN+i] * g[n*384+goff+u]
//        3 = invariants of x on the fly: A[n][u] = inv_u(x[n,:])  (K=384)
// EPI:   0 = silu(acc + bias[col]) -> Cf f32 row-major
//        1 = acc*scale (+bias[col] if bias) -> Cbf bf16 row-major
//        2 = acc*scale + fii[oidx] -> outf f32 at e3nn layout n*1152+ooff+col*SPAN+i
// ---------------------------------------------------------------------------
template<int AMODE, int EPI, int SPAN>
__global__ __launch_bounds__(256) void gemm_k(
    const bf16* __restrict__ Abf,
    const float* __restrict__ Bw, const float* __restrict__ bias,
    float* __restrict__ Cf, bf16* __restrict__ Cbf,
    int Nn, int K,
    const float* __restrict__ xsrc, const float* __restrict__ gsrc,
    int xoff, int goff, float scale,
    const float* __restrict__ fii, float* __restrict__ outf, int ooff)
{
    __shared__ float As[16][129];
    __shared__ float Bs[16][129];
    const int tid = threadIdx.x;
    const int bm = blockIdx.y * 128, bn = blockIdx.x * 128;
    const int trow = (tid >> 4) * 8;
    const int tcol = (tid & 15) * 4;
    float acc[8][8] = {};
    for (int k0 = 0; k0 < K; k0 += 16) {
        #pragma unroll
        for (int t = 0; t < 8; ++t) {
            int idx = tid + t * 256;
            int c = idx & 15, r = idx >> 4;
            float v;
            if (AMODE == 1) {
                v = __bfloat162float(Abf[(size_t)(bm + r) * K + k0 + c]);
            } else if (AMODE == 2) {
                int R = bm + r;
                int n = R / SPAN, i = R - n * SPAN;
                int u = k0 + c;
                v = xsrc[(size_t)n * 1152 + xoff + u * SPAN + i]
                  * gsrc[(size_t)n * 384 + goff + u];
            } else { // AMODE 3: invariants computed on the fly
                int n = bm + r;
                int u = k0 + c;
                const float* p = xsrc + (size_t)n * 1152;
                if (u < 128) {
                    v = p[u];
                } else if (u < 256) {
                    const float* q = p + 128 + (u - 128) * 3;
                    v = sqrtf(q[0]*q[0] + q[1]*q[1] + q[2]*q[2]);
                } else {
                    const float* q = p + 512 + (u - 256) * 5;
                    v = sqrtf(q[0]*q[0] + q[1]*q[1] + q[2]*q[2] + q[3]*q[3] + q[4]*q[4]);
                }
            }
            As[c][r] = v;
        }
        #pragma unroll
        for (int t = 0; t < 8; ++t) {
            int idx = tid + t * 256;
            int col = idx & 127, rr = idx >> 7;
            Bs[rr][col] = Bw[(size_t)(k0 + rr) * Nn + bn + col];
        }
        __syncthreads();
        #pragma unroll
        for (int kk = 0; kk < 16; ++kk) {
            float a[8], b[8];
            #pragma unroll
            for (int m = 0; m < 8; ++m) a[m] = As[kk][trow + m];
            #pragma unroll
            for (int j = 0; j < 4; ++j) { b[j] = Bs[kk][tcol + j]; b[j + 4] = Bs[kk][64 + tcol + j]; }
            #pragma unroll
            for (int m = 0; m < 8; ++m)
                #pragma unroll
                for (int j = 0; j < 8; ++j) acc[m][j] += a[m] * b[j];
        }
        __syncthreads();
    }
    #pragma unroll
    for (int m = 0; m < 8; ++m) {
        int row = bm + trow + m;
        #pragma unroll
        for (int j = 0; j < 8; ++j) {
            int col = bn + ((j < 4) ? (tcol + j) : (64 + tcol + j - 4));
            float z = acc[m][j];
            if (EPI == 0) {
                z += bias[col];
                z = z / (1.f + expf(-z));
                Cf[(size_t)row * Nn + col] = z;
            } else if (EPI == 1) {
                z = z * scale + (bias ? bias[col] : 0.f);
                Cbf[(size_t)row * Nn + col] = __float2bfloat16(z);
            } else {
                int n = row / SPAN, i = row - (row / SPAN) * SPAN;
                size_t oidx = (size_t)n * 1152 + ooff + (size_t)col * SPAN + i;
                outf[oidx] = z * scale + fii[oidx];
            }
        }
    }
}

// ---------------------------------------------------------------------------
// TP kernel: thread = (n,u).  phase 0: write invariants [Nc][1408].
// phase 1: apply gate gp, write grouped i-major tpg buffers.
// xl/xr layout (bf16): l0 at [n*128+u]; l1 at Nc*128 + (n*3+i)*128+u; l2 at Nc*512 + (n*5+i)*128+u
// ---------------------------------------------------------------------------
__global__ __launch_bounds__(256) void tp_kernel(
    const bf16* __restrict__ xl, const bf16* __restrict__ xr,
    const float* __restrict__ tp_w, const float* __restrict__ gp,
    bf16* __restrict__ inv_tp,
    bf16* __restrict__ tpg0, bf16* __restrict__ tpg1, bf16* __restrict__ tpg2,
    W3JPack w3j, int phase, int Nc)
{
    int idx = blockIdx.x * 256 + threadIdx.x;
    int n = idx >> 7, u = idx & 127;
    const size_t O1 = (size_t)Nc * 128, O2 = (size_t)Nc * 512;
    float XL[3][5], XR[3][5];
    XL[0][0] = __bfloat162float(xl[(size_t)n * 128 + u]);
    XR[0][0] = __bfloat162float(xr[(size_t)n * 128 + u]);
    #pragma unroll
    for (int i = 0; i < 3; ++i) {
        XL[1][i] = __bfloat162float(xl[O1 + ((size_t)n * 3 + i) * 128 + u]);
        XR[1][i] = __bfloat162float(xr[O1 + ((size_t)n * 3 + i) * 128 + u]);
    }
    #pragma unroll
    for (int i = 0; i < 5; ++i) {
        XL[2][i] = __bfloat162float(xl[O2 + ((size_t)n * 5 + i) * 128 + u]);
        XR[2][i] = __bfloat162float(xr[O2 + ((size_t)n * 5 + i) * 128 + u]);
    }
    const float SQF[3] = {1.f, 1.7320508075688772f, 2.2360679774997896f};
    #pragma unroll
    for (int p = 0; p < 11; ++p) {
        const int l1 = P_L1[p], l2 = P_L2[p], lo = P_LO[p];
        const int d1 = 2*l1+1, d2 = 2*l2+1, dd = 2*lo+1;
        const float* W = &w3j.v[P_OFF[p]];
        float tw = tp_w[p * 128 + u] * SQF[lo];
        float o[5];
        #pragma unroll
        for (int k = 0; k < dd; ++k) {
            float a = 0.f;
            #pragma unroll
            for (int i = 0; i < d1; ++i)
                #pragma unroll
                for (int jj = 0; jj < d2; ++jj)
                    a += W[(i * d2 + jj) * dd + k] * XL[l1][i] * XR[l2][jj];
            o[k] = a * tw;
        }
        if (phase == 0) {
            float iv;
            if (lo == 0) iv = o[0];
            else {
                float s = 0.f;
                #pragma unroll
                for (int k = 0; k < dd; ++k) s += o[k] * o[k];
                iv = sqrtf(s);
            }
            inv_tp[(size_t)n * 1408 + p * 128 + u] = __float2bfloat16(iv);
        } else {
            float g = gp[(size_t)n * 1408 + p * 128 + u];
            int gg = P_G[p];
            if (lo == 0) {
                tpg0[(size_t)n * 384 + gg * 128 + u] = __float2bfloat16(o[0] * g);
            } else if (lo == 1) {
                #pragma unroll
                for (int k = 0; k < 3; ++k)
                    tpg1[((size_t)n * 3 + k) * 512 + gg * 128 + u] = __float2bfloat16(o[k] * g);
            } else {
                #pragma unroll
                for (int k = 0; k < 5; ++k)
                    tpg2[((size_t)n * 5 + k) * 512 + gg * 128 + u] = __float2bfloat16(o[k] * g);
            }
        }
    }
}

// ---------------------------------------------------------------------------
// Host: real-basis Wigner 3j (exact port of the reference math)
// ---------------------------------------------------------------------------
static double factd(int n) {
    static const double F[10] = {1,1,2,6,24,120,720,5040,40320,362880};
    return F[n];
}

static double su2_cg(int j1,int m1,int j2,int m2,int j3,int m3){
    if (m3 != m1 + m2) return 0.0;
    int vmin = std::max(std::max(-j1 + j2 + m3, -j1 + m1), 0);
    int vmax = std::min(std::min(j2 + j3 + m1, j3 - j1 + j2), j3 + m3);
    if (vmax < vmin) return 0.0;
    double c = std::sqrt((2*j3+1) * factd(j3+j1-j2) * factd(j3-j1+j2) * factd(j1+j2-j3)
               * factd(j3+m3) * factd(j3-m3)
               / (factd(j1+j2+j3+1) * factd(j1-m1) * factd(j1+m1) * factd(j2-m2) * factd(j2+m2)));
    double s = 0.0;
    for (int v = vmin; v <= vmax; ++v) {
        double sg = ((v + j2 + m2) & 1) ? -1.0 : 1.0;
        s += sg * factd(j2+j3+m1-v) * factd(j1-m1+v)
             / (factd(v) * factd(j3-j1+j2-v) * factd(j3+m3-v) * factd(v+j1-j2-m3));
    }
    return c * s;
}

typedef std::complex<double> cd;

static void q_matrix(int l, cd* q) {
    int d = 2*l+1;
    for (int i = 0; i < d*d; ++i) q[i] = cd(0,0);
    const double is2 = 1.0 / std::sqrt(2.0);
    for (int m = -l; m < 0; ++m) {
        q[(l+m)*d + (l-m)] = cd(is2, 0);
        q[(l+m)*d + (l+m)] = cd(0, -is2);
    }
    q[l*d + l] = cd(1,0);
    for (int m = 1; m <= l; ++m) {
        double sg = (m & 1) ? -1.0 : 1.0;
        q[(l+m)*d + (l+m)] = cd(sg*is2, 0);
        q[(l+m)*d + (l-m)] = cd(0, sg*is2);
    }
    cd f = (l==0) ? cd(1,0) : (l==1) ? cd(0,-1) : cd(-1,0);
    for (int i = 0; i < d*d; ++i) q[i] *= f;
}

static void compute_w3j(float* out) {
    for (int p = 0; p < 11; ++p) {
        int l1 = P_L1[p], l2 = P_L2[p], l3 = P_LO[p];
        int d1 = 2*l1+1, d2 = 2*l2+1, d3 = 2*l3+1;
        cd q1[25], q2[25], q3[25];
        q_matrix(l1, q1); q_matrix(l2, q2); q_matrix(l3, q3);
        double nrm = std::sqrt((double)d3);
        for (int a = 0; a < d1; ++a)
        for (int b = 0; b < d2; ++b)
        for (int c = 0; c < d3; ++c) {
            cd s(0,0);
            for (int i = 0; i < d1; ++i)
            for (int k = 0; k < d2; ++k)
            for (int m = 0; m < d3; ++m) {
                double cg = su2_cg(l1, i-l1, l2, k-l2, l3, m-l3);
                if (cg == 0.0) continue;
                s += q1[i*d1 + a] * q2[k*d2 + b] * std::conj(q3[m*d3 + c]) * cg;
            }
            out[P_OFF[p] + (a*d2 + b)*d3 + c] = (float)(s.real() / nrm);
        }
    }
}

// ---------------------------------------------------------------------------
extern "C" void kernel_launch(void* const* d_in, const int* in_sizes, int n_in,
                              void* d_out, int out_size, void* d_ws, size_t ws_size,
                              hipStream_t stream)
{
    (void)in_sizes; (void)n_in; (void)out_size;
    const float* x    = (const float*)d_in[0];
    const float* fii  = (const float*)d_in[1];
    const float* Wg_l = (const float*)d_in[2];
    const float* bg_l = (const float*)d_in[3];
    const float* Wl0  = (const float*)d_in[4];
    const float* Wl1  = (const float*)d_in[5];
    const float* Wl2  = (const float*)d_in[6];
    const float* bl0  = (const float*)d_in[7];
    const float* Wg_r = (const float*)d_in[8];
    const float* bg_r = (const float*)d_in[9];
    const float* Wr0  = (const float*)d_in[10];
    const float* Wr1  = (const float*)d_in[11];
    const float* Wr2  = (const float*)d_in[12];
    const float* br0  = (const float*)d_in[13];
    const float* tp_w = (const float*)d_in[14];
    const float* Wg_p = (const float*)d_in[15];
    const float* bg_p = (const float*)d_in[16];
    const float* Wp0  = (const float*)d_in[17];
    const float* Wp1  = (const float*)d_in[18];
    const float* Wp2  = (const float*)d_in[19];
    float* out = (float*)d_out;

    W3JPack w3j;
    compute_w3j(w3j.v);

    // ---- choose node-chunking so the workspace fits ws_size ----
    auto al = [](size_t b) { return (b + 255) & ~(size_t)255; };
    int c = 1;
    size_t Nc, b_xl, b_scrA, b_gp, b_tpg1, b_tpg2;
    for (;; c *= 2) {
        Nc = NN / c;
        b_xl   = al(Nc * 1152 * 2);        // xl (and xr) bf16
        b_scrA = al(Nc * 384 * 4 * 2);     // gl+gr f32 (>= inv_tp bf16 Nc*2816, >= tpg0 Nc*768)
        b_gp   = al(Nc * 1408 * 4);        // gp f32
        b_tpg1 = al(Nc * 1536 * 2);
        b_tpg2 = al(Nc * 2560 * 2);
        size_t total = 2 * b_xl + b_scrA + b_gp + b_tpg1 + b_tpg2;
        if (total <= ws_size || c >= 32) break;
    }

    char* base = (char*)d_ws;
    bf16*  xl     = (bf16*)base;
    bf16*  xr     = (bf16*)(base + b_xl);
    char*  scrA   = base + 2 * b_xl;
    float* gl     = (float*)scrA;                       // live K2 -> K3
    float* gr     = (float*)(scrA + Nc * 384 * 4);
    bf16*  inv_tp = (bf16*)scrA;                        // live K4 -> K5 (aliases gl/gr)
    bf16*  tpg0   = (bf16*)scrA;                        // live K4b -> K6 (aliases inv_tp)
    float* gp     = (float*)(scrA + b_scrA);
    bf16*  tpg1   = (bf16*)(scrA + b_scrA + b_gp);
    bf16*  tpg2   = (bf16*)(scrA + b_scrA + b_gp + b_tpg1);

    const float s128 = 0.08838834764831845f;   // 1/sqrt(128)
    const float s384 = 0.05103103630798287f;   // 1/sqrt(384)
    const float s512 = 0.044194173824159216f;  // 1/sqrt(512)
    dim3 blk(256);
    const int gy = (int)(Nc / 128);

    for (int ch = 0; ch < c; ++ch) {
        const float* xc = x   + (size_t)ch * Nc * 1152;
        const float* fc = fii + (size_t)ch * Nc * 1152;
        float*       oc = out + (size_t)ch * Nc * 1152;

        // K2: gate logits + silu -> gl, gr (f32 [Nc][384]); invariants computed in-loader
        gemm_k<3,0,1><<<dim3(3,gy), blk, 0, stream>>>(nullptr, Wg_l, bg_l, gl, nullptr,
            384, 384, xc, nullptr, 0, 0, 0.f, nullptr, nullptr, 0);
        gemm_k<3,0,1><<<dim3(3,gy), blk, 0, stream>>>(nullptr, Wg_r, bg_r, gr, nullptr,
            384, 384, xc, nullptr, 0, 0, 0.f, nullptr, nullptr, 0);

        // K3: gated linear_sq -> xl, xr (bf16, i-major per l region)
        gemm_k<2,1,1><<<dim3(1,gy),   blk, 0, stream>>>(nullptr, Wl0, bl0, nullptr, xl,
            128, 128, xc, gl, 0, 0, s128, nullptr, nullptr, 0);
        gemm_k<2,1,3><<<dim3(1,3*gy), blk, 0, stream>>>(nullptr, Wl1, nullptr, nullptr, xl + Nc*128,
            128, 128, xc, gl, 128, 128, s128, nullptr, nullptr, 0);
        gemm_k<2,1,5><<<dim3(1,5*gy), blk, 0, stream>>>(nullptr, Wl2, nullptr, nullptr, xl + Nc*512,
            128, 128, xc, gl, 512, 256, s128, nullptr, nullptr, 0);
        gemm_k<2,1,1><<<dim3(1,gy),   blk, 0, stream>>>(nullptr, Wr0, br0, nullptr, xr,
            128, 128, xc, gr, 0, 0, s128, nullptr, nullptr, 0);
        gemm_k<2,1,3><<<dim3(1,3*gy), blk, 0, stream>>>(nullptr, Wr1, nullptr, nullptr, xr + Nc*128,
            128, 128, xc, gr, 128, 128, s128, nullptr, nullptr, 0);
        gemm_k<2,1,5><<<dim3(1,5*gy), blk, 0, stream>>>(nullptr, Wr2, nullptr, nullptr, xr + Nc*512,
            128, 128, xc, gr, 512, 256, s128, nullptr, nullptr, 0);

        // K4: TP -> invariants (phase 0)  (writes inv_tp over dead gl/gr)
        tp_kernel<<<dim3((int)(Nc/2)), blk, 0, stream>>>(xl, xr, tp_w, gp, inv_tp,
            tpg0, tpg1, tpg2, w3j, 0, (int)Nc);

        // K5: gate_p GEMM: gp = silu(inv_tp @ Wg_p + bg_p)
        gemm_k<1,0,1><<<dim3(11,gy), blk, 0, stream>>>(inv_tp, Wg_p, bg_p, gp, nullptr,
            1408, 1408, nullptr, nullptr, 0, 0, 0.f, nullptr, nullptr, 0);

        // K4b: TP recompute + gate apply -> tpg (tpg0 over dead inv_tp)
        tp_kernel<<<dim3((int)(Nc/2)), blk, 0, stream>>>(xl, xr, tp_w, gp, inv_tp,
            tpg0, tpg1, tpg2, w3j, 1, (int)Nc);

        // K6: linear_p + fii -> out (f32, e3nn layout)
        gemm_k<1,2,1><<<dim3(1,gy),   blk, 0, stream>>>(tpg0, Wp0, nullptr, nullptr, nullptr,
            128, 384, nullptr, nullptr, 0, 0, s384, fc, oc, 0);
        gemm_k<1,2,3><<<dim3(1,3*gy), blk, 0, stream>>>(tpg1, Wp1, nullptr, nullptr, nullptr,
            128, 512, nullptr, nullptr, 0, 0, s512, fc, oc, 128);
        gemm_k<1,2,5><<<dim3(1,5*gy), blk, 0, stream>>>(tpg2, Wp2, nullptr, nullptr, nullptr,
            128, 512, nullptr, nullptr, 0, 0, s512, fc, oc, 512);
    }
}

// Round 3
// 869.079 us; speedup vs baseline: 3.8297x; 3.8297x over previous
//
#include <hip/hip_runtime.h>
#include <hip/hip_bf16.h>
#include <cmath>
#include <complex>
#include <algorithm>

typedef __hip_bfloat16 bf16;
typedef __bf16 bf16x8 __attribute__((ext_vector_type(8)));
typedef float f32x4 __attribute__((ext_vector_type(4)));

#define NN 16384

constexpr int P_L1[11] = {0,0,0,1,1,1,1,2,2,2,2};
constexpr int P_L2[11] = {0,1,2,0,1,1,2,0,1,2,2};
constexpr int P_LO[11] = {0,1,2,1,0,2,1,2,1,0,2};
constexpr int P_OFF[11]= {0,1,10,35,44,53,98,143,168,213,238}; // sizes 1,9,25,9,9,45,45,25,45,25,125 -> 363
constexpr int P_G[11]  = {0,0,0,1,1,1,2,2,3,2,3};

struct W3JPack { float v[363]; };

// ---------------------------------------------------------------------------
// invariants of x -> bf16 [Nc][384]
// ---------------------------------------------------------------------------
__global__ __launch_bounds__(256) void invx_kernel(const float* __restrict__ x,
                                                   bf16* __restrict__ inv_x)
{
    int idx = blockIdx.x * 256 + threadIdx.x;
    int n = idx / 384, c = idx - n * 384;
    const float* p = x + (size_t)n * 1152;
    float v;
    if (c < 128) {
        v = p[c];
    } else if (c < 256) {
        const float* q = p + 128 + (c - 128) * 3;
        v = sqrtf(q[0]*q[0] + q[1]*q[1] + q[2]*q[2]);
    } else {
        const float* q = p + 512 + (c - 256) * 5;
        v = sqrtf(q[0]*q[0] + q[1]*q[1] + q[2]*q[2] + q[3]*q[3] + q[4]*q[4]);
    }
    inv_x[idx] = __float2bfloat16(v);
}

// ---------------------------------------------------------------------------
// weight convert+transpose: W f32 [K][Nn] -> Bt bf16 [Nn][K]
// ---------------------------------------------------------------------------
__global__ __launch_bounds__(256) void wconv(const float* __restrict__ W,
                                             bf16* __restrict__ Bt, int K, int Nn)
{
    __shared__ float t[32][33];
    int bx = blockIdx.x * 32;  // n tile
    int by = blockIdx.y * 32;  // k tile
    int lx = threadIdx.x & 31, ly = threadIdx.x >> 5;
    #pragma unroll
    for (int yy = ly; yy < 32; yy += 8)
        t[yy][lx] = W[(size_t)(by + yy) * Nn + bx + lx];
    __syncthreads();
    #pragma unroll
    for (int yy = ly; yy < 32; yy += 8)
        Bt[(size_t)(bx + yy) * K + by + lx] = __float2bfloat16(t[lx][yy]);
}

// ---------------------------------------------------------------------------
// gated-x materialize: xg[(n,i)][u] = x[n,xoff+u*SPAN+i] * g[n,goff+u]  (bf16)
// regions: l0 @0 [Nc][128]; l1 @Nc*128 [(3Nc)][128]; l2 @Nc*512 [(5Nc)][128]
// ---------------------------------------------------------------------------
__global__ __launch_bounds__(256) void gate_apply(const float* __restrict__ x,
                                                  const float* __restrict__ g,
                                                  bf16* __restrict__ xg, int Nc)
{
    int idx = blockIdx.x * 256 + threadIdx.x;
    int n = idx >> 7, u = idx & 127;
    const float* xrow = x + (size_t)n * 1152;
    const float* grow = g + (size_t)n * 384;
    size_t O1 = (size_t)Nc * 128, O2 = (size_t)Nc * 512;
    float g0 = grow[u], g1 = grow[128 + u], g2 = grow[256 + u];
    xg[(size_t)n * 128 + u] = __float2bfloat16(xrow[u] * g0);
    #pragma unroll
    for (int i = 0; i < 3; ++i)
        xg[O1 + ((size_t)n * 3 + i) * 128 + u] = __float2bfloat16(xrow[128 + u * 3 + i] * g1);
    #pragma unroll
    for (int i = 0; i < 5; ++i)
        xg[O2 + ((size_t)n * 5 + i) * 128 + u] = __float2bfloat16(xrow[512 + u * 5 + i] * g2);
}

// ---------------------------------------------------------------------------
// MFMA GEMM: C[M][Nn] = A[M][K](bf16) * Bt[Nn][K](bf16)^T
// 128x128 tile, BK=64, 256 thr (4 waves, 2x2), 4x4 16x16x32 frags per wave.
// global_load_lds staging, XOR-swizzled LDS (byte ^= (row&7)<<4).
// EPI 0: silu(acc + bias[col]) -> Cf f32
// EPI 1: acc*scale (+bias[col] if bias) -> Cbf bf16
// EPI 2: acc*scale + fii[oidx] -> outf f32 at n*1152+ooff+col*SPAN+i, row=(n,i)
// ---------------------------------------------------------------------------
template<int EPI, int SPAN>
__global__ __launch_bounds__(256) void mgemm(
    const bf16* __restrict__ A, const bf16* __restrict__ Bt,
    const float* __restrict__ bias,
    float* __restrict__ Cf, bf16* __restrict__ Cbf,
    int Nn, int K, float scale,
    const float* __restrict__ fii, float* __restrict__ outf, int ooff)
{
    __shared__ __align__(16) char Lds[32768];
    char* AsB = Lds;
    char* BsB = Lds + 16384;
    const int tid  = threadIdx.x;
    const int lane = tid & 63;
    const int wid  = tid >> 6;
    const int bm = blockIdx.y * 128;
    const int bn = blockIdx.x * 128;
    const int wm = (wid >> 1) * 64;
    const int wn = (wid & 1) * 64;

    // staging source coords for the 4 per-wave 1KB chunks
    int srow[4], scol[4];
    #pragma unroll
    for (int q = 0; q < 4; ++q) {
        int d = wid * 4096 + q * 1024 + lane * 16;
        int row = d >> 7;
        int colb = (d & 127) ^ ((row & 7) << 4);
        srow[q] = row;
        scol[q] = colb >> 1;
    }

    f32x4 acc[4][4];
    #pragma unroll
    for (int m = 0; m < 4; ++m)
        #pragma unroll
        for (int n = 0; n < 4; ++n)
            acc[m][n] = (f32x4){0.f, 0.f, 0.f, 0.f};

    for (int k0 = 0; k0 < K; k0 += 64) {
        #pragma unroll
        for (int q = 0; q < 4; ++q) {
            const bf16* ga = A + (size_t)(bm + srow[q]) * K + k0 + scol[q];
            __builtin_amdgcn_global_load_lds(
                (const __attribute__((address_space(1))) void*)ga,
                (__attribute__((address_space(3))) void*)(AsB + wid * 4096 + q * 1024),
                16, 0, 0);
            const bf16* gb = Bt + (size_t)(bn + srow[q]) * K + k0 + scol[q];
            __builtin_amdgcn_global_load_lds(
                (const __attribute__((address_space(1))) void*)gb,
                (__attribute__((address_space(3))) void*)(BsB + wid * 4096 + q * 1024),
                16, 0, 0);
        }
        asm volatile("s_waitcnt vmcnt(0)" ::: "memory");
        __syncthreads();
        #pragma unroll
        for (int kh = 0; kh < 2; ++kh) {
            bf16x8 av[4], bv[4];
            #pragma unroll
            for (int m = 0; m < 4; ++m) {
                int row = wm + m * 16 + (lane & 15);
                int off = row * 128 + kh * 64 + ((lane >> 4) << 4);
                off ^= (row & 7) << 4;
                av[m] = *reinterpret_cast<const bf16x8*>(AsB + off);
            }
            #pragma unroll
            for (int n = 0; n < 4; ++n) {
                int row = wn + n * 16 + (lane & 15);
                int off = row * 128 + kh * 64 + ((lane >> 4) << 4);
                off ^= (row & 7) << 4;
                bv[n] = *reinterpret_cast<const bf16x8*>(BsB + off);
            }
            #pragma unroll
            for (int m = 0; m < 4; ++m)
                #pragma unroll
                for (int n = 0; n < 4; ++n)
                    acc[m][n] = __builtin_amdgcn_mfma_f32_16x16x32_bf16(av[m], bv[n], acc[m][n], 0, 0, 0);
        }
        __syncthreads();
    }

    // epilogue: D lane map col=lane&15, row=4*(lane>>4)+r  [measured m89]
    #pragma unroll
    for (int m = 0; m < 4; ++m) {
        int row0 = bm + wm + m * 16 + ((lane >> 4) << 2);
        #pragma unroll
        for (int n = 0; n < 4; ++n) {
            int col = bn + wn + n * 16 + (lane & 15);
            #pragma unroll
            for (int r = 0; r < 4; ++r) {
                int row = row0 + r;
                float z = acc[m][n][r];
                if (EPI == 0) {
                    z += bias[col];
                    z = z / (1.f + __expf(-z));
                    Cf[(size_t)row * Nn + col] = z;
                } else if (EPI == 1) {
                    z = z * scale + (bias ? bias[col] : 0.f);
                    Cbf[(size_t)row * Nn + col] = __float2bfloat16(z);
                } else {
                    int nn = row / SPAN, i = row - nn * SPAN;
                    size_t oidx = (size_t)nn * 1152 + ooff + (size_t)col * SPAN + i;
                    outf[oidx] = z * scale + fii[oidx];
                }
            }
        }
    }
}

// ---------------------------------------------------------------------------
// TP kernel: thread=(n,u). phase 0: invariants bf16 [Nc][1408];
// phase 1: apply gate gp, write grouped i-major tpg (bf16).
// ---------------------------------------------------------------------------
__global__ __launch_bounds__(256) void tp_kernel(
    const bf16* __restrict__ xl, const bf16* __restrict__ xr,
    const float* __restrict__ tp_w, const float* __restrict__ gp,
    bf16* __restrict__ inv_tp,
    bf16* __restrict__ tpg0, bf16* __restrict__ tpg1, bf16* __restrict__ tpg2,
    W3JPack w3j, int phase, int Nc)
{
    int idx = blockIdx.x * 256 + threadIdx.x;
    int n = idx >> 7, u = idx & 127;
    const size_t O1 = (size_t)Nc * 128, O2 = (size_t)Nc * 512;
    float XL[3][5], XR[3][5];
    XL[0][0] = __bfloat162float(xl[(size_t)n * 128 + u]);
    XR[0][0] = __bfloat162float(xr[(size_t)n * 128 + u]);
    #pragma unroll
    for (int i = 0; i < 3; ++i) {
        XL[1][i] = __bfloat162float(xl[O1 + ((size_t)n * 3 + i) * 128 + u]);
        XR[1][i] = __bfloat162float(xr[O1 + ((size_t)n * 3 + i) * 128 + u]);
    }
    #pragma unroll
    for (int i = 0; i < 5; ++i) {
        XL[2][i] = __bfloat162float(xl[O2 + ((size_t)n * 5 + i) * 128 + u]);
        XR[2][i] = __bfloat162float(xr[O2 + ((size_t)n * 5 + i) * 128 + u]);
    }
    const float SQF[3] = {1.f, 1.7320508075688772f, 2.2360679774997896f};
    #pragma unroll
    for (int p = 0; p < 11; ++p) {
        const int l1 = P_L1[p], l2 = P_L2[p], lo = P_LO[p];
        const int d1 = 2*l1+1, d2 = 2*l2+1, dd = 2*lo+1;
        const float* W = &w3j.v[P_OFF[p]];
        float tw = tp_w[p * 128 + u] * SQF[lo];
        float o[5];
        #pragma unroll
        for (int k = 0; k < dd; ++k) {
            float a = 0.f;
            #pragma unroll
            for (int i = 0; i < d1; ++i)
                #pragma unroll
                for (int jj = 0; jj < d2; ++jj)
                    a += W[(i * d2 + jj) * dd + k] * XL[l1][i] * XR[l2][jj];
            o[k] = a * tw;
        }
        if (phase == 0) {
            float iv;
            if (lo == 0) iv = o[0];
            else {
                float s = 0.f;
                #pragma unroll
                for (int k = 0; k < dd; ++k) s += o[k] * o[k];
                iv = sqrtf(s);
            }
            inv_tp[(size_t)n * 1408 + p * 128 + u] = __float2bfloat16(iv);
        } else {
            float g = gp[(size_t)n * 1408 + p * 128 + u];
            int gg = P_G[p];
            if (lo == 0) {
                tpg0[(size_t)n * 384 + gg * 128 + u] = __float2bfloat16(o[0] * g);
            } else if (lo == 1) {
                #pragma unroll
                for (int k = 0; k < 3; ++k)
                    tpg1[((size_t)n * 3 + k) * 512 + gg * 128 + u] = __float2bfloat16(o[k] * g);
            } else {
                #pragma unroll
                for (int k = 0; k < 5; ++k)
                    tpg2[((size_t)n * 5 + k) * 512 + gg * 128 + u] = __float2bfloat16(o[k] * g);
            }
        }
    }
}

// ---------------------------------------------------------------------------
// Host: real-basis Wigner 3j (exact port of the reference math)
// ---------------------------------------------------------------------------
static double factd(int n) {
    static const double F[10] = {1,1,2,6,24,120,720,5040,40320,362880};
    return F[n];
}

static double su2_cg(int j1,int m1,int j2,int m2,int j3,int m3){
    if (m3 != m1 + m2) return 0.0;
    int vmin = std::max(std::max(-j1 + j2 + m3, -j1 + m1), 0);
    int vmax = std::min(std::min(j2 + j3 + m1, j3 - j1 + j2), j3 + m3);
    if (vmax < vmin) return 0.0;
    double c = std::sqrt((2*j3+1) * factd(j3+j1-j2) * factd(j3-j1+j2) * factd(j1+j2-j3)
               * factd(j3+m3) * factd(j3-m3)
               / (factd(j1+j2+j3+1) * factd(j1-m1) * factd(j1+m1) * factd(j2-m2) * factd(j2+m2)));
    double s = 0.0;
    for (int v = vmin; v <= vmax; ++v) {
        double sg = ((v + j2 + m2) & 1) ? -1.0 : 1.0;
        s += sg * factd(j2+j3+m1-v) * factd(j1-m1+v)
             / (factd(v) * factd(j3-j1+j2-v) * factd(j3+m3-v) * factd(v+j1-j2-m3));
    }
    return c * s;
}

typedef std::complex<double> cd;

static void q_matrix(int l, cd* q) {
    int d = 2*l+1;
    for (int i = 0; i < d*d; ++i) q[i] = cd(0,0);
    const double is2 = 1.0 / std::sqrt(2.0);
    for (int m = -l; m < 0; ++m) {
        q[(l+m)*d + (l-m)] = cd(is2, 0);
        q[(l+m)*d + (l+m)] = cd(0, -is2);
    }
    q[l*d + l] = cd(1,0);
    for (int m = 1; m <= l; ++m) {
        double sg = (m & 1) ? -1.0 : 1.0;
        q[(l+m)*d + (l+m)] = cd(sg*is2, 0);
        q[(l+m)*d + (l-m)] = cd(0, sg*is2);
    }
    cd f = (l==0) ? cd(1,0) : (l==1) ? cd(0,-1) : cd(-1,0);
    for (int i = 0; i < d*d; ++i) q[i] *= f;
}

static void compute_w3j(float* out) {
    for (int p = 0; p < 11; ++p) {
        int l1 = P_L1[p], l2 = P_L2[p], l3 = P_LO[p];
        int d1 = 2*l1+1, d2 = 2*l2+1, d3 = 2*l3+1;
        cd q1[25], q2[25], q3[25];
        q_matrix(l1, q1); q_matrix(l2, q2); q_matrix(l3, q3);
        double nrm = std::sqrt((double)d3);
        for (int a = 0; a < d1; ++a)
        for (int b = 0; b < d2; ++b)
        for (int c = 0; c < d3; ++c) {
            cd s(0,0);
            for (int i = 0; i < d1; ++i)
            for (int k = 0; k < d2; ++k)
            for (int m = 0; m < d3; ++m) {
                double cg = su2_cg(l1, i-l1, l2, k-l2, l3, m-l3);
                if (cg == 0.0) continue;
                s += q1[i*d1 + a] * q2[k*d2 + b] * std::conj(q3[m*d3 + c]) * cg;
            }
            out[P_OFF[p] + (a*d2 + b)*d3 + c] = (float)(s.real() / nrm);
        }
    }
}

// ---------------------------------------------------------------------------
extern "C" void kernel_launch(void* const* d_in, const int* in_sizes, int n_in,
                              void* d_out, int out_size, void* d_ws, size_t ws_size,
                              hipStream_t stream)
{
    (void)in_sizes; (void)n_in; (void)out_size;
    const float* x    = (const float*)d_in[0];
    const float* fii  = (const float*)d_in[1];
    const float* Wg_l = (const float*)d_in[2];
    const float* bg_l = (const float*)d_in[3];
    const float* Wl0  = (const float*)d_in[4];
    const float* Wl1  = (const float*)d_in[5];
    const float* Wl2  = (const float*)d_in[6];
    const float* bl0  = (const float*)d_in[7];
    const float* Wg_r = (const float*)d_in[8];
    const float* bg_r = (const float*)d_in[9];
    const float* Wr0  = (const float*)d_in[10];
    const float* Wr1  = (const float*)d_in[11];
    const float* Wr2  = (const float*)d_in[12];
    const float* br0  = (const float*)d_in[13];
    const float* tp_w = (const float*)d_in[14];
    const float* Wg_p = (const float*)d_in[15];
    const float* bg_p = (const float*)d_in[16];
    const float* Wp0  = (const float*)d_in[17];
    const float* Wp1  = (const float*)d_in[18];
    const float* Wp2  = (const float*)d_in[19];
    float* out = (float*)d_out;

    W3JPack w3j;
    compute_w3j(w3j.v);

    auto al = [](size_t b) { return (b + 255) & ~(size_t)255; };
    char* base = (char*)d_ws;
    size_t woff = 0;
    auto walloc = [&](size_t elems) { void* p = base + woff; woff += al(elems * 2); return (bf16*)p; };
    bf16* tWg_l = walloc(384 * 384);
    bf16* tWg_r = walloc(384 * 384);
    bf16* tWl0  = walloc(128 * 128);
    bf16* tWl1  = walloc(128 * 128);
    bf16* tWl2  = walloc(128 * 128);
    bf16* tWr0  = walloc(128 * 128);
    bf16* tWr1  = walloc(128 * 128);
    bf16* tWr2  = walloc(128 * 128);
    bf16* tWg_p = walloc((size_t)1408 * 1408);
    bf16* tWp0  = walloc(128 * 384);
    bf16* tWp1  = walloc(128 * 512);
    bf16* tWp2  = walloc(128 * 512);
    const size_t wtotal = woff;

    int c = 1; size_t Nc;
    for (;; c *= 2) {
        Nc = NN / c;
        size_t tot = wtotal + al(Nc*4608) + 2*al(Nc*2304) + al(Nc*5632) + al(Nc*5120);
        if (tot <= ws_size || c >= 32) break;
    }
    char* cb = base + wtotal;
    char* pool   = cb;                           cb += al(Nc * 4608);
    bf16*  inv_x  = (bf16*)pool;                  // [0, 768Nc)    P1 -> K2r
    float* gbuf   = (float*)(pool + Nc * 768);    // [768Nc,2304Nc) K2 -> P2 (per side)
    bf16*  xg     = (bf16*)(pool + Nc * 2304);    // [2304Nc,4608Nc) P2 -> K3 (per side)
    bf16*  inv_tp = (bf16*)pool;                  // [0,2816Nc)    K4 -> K5
    bf16*  tpg0   = (bf16*)pool;                  // [0,768Nc)     K4b -> K6
    bf16*  tpg1   = (bf16*)(pool + Nc * 768);     // [768Nc,3840Nc)
    bf16*  xl = (bf16*)cb;  cb += al(Nc * 2304);
    bf16*  xr = (bf16*)cb;  cb += al(Nc * 2304);
    float* gp = (float*)cb; cb += al(Nc * 5632);
    bf16*  tpg2 = (bf16*)cb;

    const float s128 = 0.08838834764831845f;   // 1/sqrt(128)
    const float s384 = 0.05103103630798287f;   // 1/sqrt(384)
    const float s512 = 0.044194173824159216f;  // 1/sqrt(512)
    dim3 blk(256);

    // weight convert+transpose (once)
    wconv<<<dim3(12,12), blk, 0, stream>>>(Wg_l, tWg_l, 384, 384);
    wconv<<<dim3(12,12), blk, 0, stream>>>(Wg_r, tWg_r, 384, 384);
    wconv<<<dim3(4,4),   blk, 0, stream>>>(Wl0, tWl0, 128, 128);
    wconv<<<dim3(4,4),   blk, 0, stream>>>(Wl1, tWl1, 128, 128);
    wconv<<<dim3(4,4),   blk, 0, stream>>>(Wl2, tWl2, 128, 128);
    wconv<<<dim3(4,4),   blk, 0, stream>>>(Wr0, tWr0, 128, 128);
    wconv<<<dim3(4,4),   blk, 0, stream>>>(Wr1, tWr1, 128, 128);
    wconv<<<dim3(4,4),   blk, 0, stream>>>(Wr2, tWr2, 128, 128);
    wconv<<<dim3(44,44), blk, 0, stream>>>(Wg_p, tWg_p, 1408, 1408);
    wconv<<<dim3(4,12),  blk, 0, stream>>>(Wp0, tWp0, 384, 128);
    wconv<<<dim3(4,16),  blk, 0, stream>>>(Wp1, tWp1, 512, 128);
    wconv<<<dim3(4,16),  blk, 0, stream>>>(Wp2, tWp2, 512, 128);

    const int gy = (int)(Nc / 128);
    for (int ch = 0; ch < c; ++ch) {
        const float* xc = x   + (size_t)ch * Nc * 1152;
        const float* fc = fii + (size_t)ch * Nc * 1152;
        float*       oc = out + (size_t)ch * Nc * 1152;

        invx_kernel<<<dim3((int)(Nc * 384 / 256)), blk, 0, stream>>>(xc, inv_x);

        // ---- left side ----
        mgemm<0,1><<<dim3(3, gy), blk, 0, stream>>>(inv_x, tWg_l, bg_l, gbuf, nullptr,
            384, 384, 0.f, nullptr, nullptr, 0);
        gate_apply<<<dim3((int)(Nc / 2)), blk, 0, stream>>>(xc, gbuf, xg, (int)Nc);
        mgemm<1,1><<<dim3(1, gy),   blk, 0, stream>>>(xg,           tWl0, bl0,     nullptr, xl,
            128, 128, s128, nullptr, nullptr, 0);
        mgemm<1,1><<<dim3(1, 3*gy), blk, 0, stream>>>(xg + Nc*128,  tWl1, nullptr, nullptr, xl + Nc*128,
            128, 128, s128, nullptr, nullptr, 0);
        mgemm<1,1><<<dim3(1, 5*gy), blk, 0, stream>>>(xg + Nc*512,  tWl2, nullptr, nullptr, xl + Nc*512,
            128, 128, s128, nullptr, nullptr, 0);

        // ---- right side (reuses gbuf, xg) ----
        mgemm<0,1><<<dim3(3, gy), blk, 0, stream>>>(inv_x, tWg_r, bg_r, gbuf, nullptr,
            384, 384, 0.f, nullptr, nullptr, 0);
        gate_apply<<<dim3((int)(Nc / 2)), blk, 0, stream>>>(xc, gbuf, xg, (int)Nc);
        mgemm<1,1><<<dim3(1, gy),   blk, 0, stream>>>(xg,           tWr0, br0,     nullptr, xr,
            128, 128, s128, nullptr, nullptr, 0);
        mgemm<1,1><<<dim3(1, 3*gy), blk, 0, stream>>>(xg + Nc*128,  tWr1, nullptr, nullptr, xr + Nc*128,
            128, 128, s128, nullptr, nullptr, 0);
        mgemm<1,1><<<dim3(1, 5*gy), blk, 0, stream>>>(xg + Nc*512,  tWr2, nullptr, nullptr, xr + Nc*512,
            128, 128, s128, nullptr, nullptr, 0);

        // ---- TP invariants, gate_p GEMM, TP gate-apply ----
        tp_kernel<<<dim3((int)(Nc / 2)), blk, 0, stream>>>(xl, xr, tp_w, gp, inv_tp,
            tpg0, tpg1, tpg2, w3j, 0, (int)Nc);
        mgemm<0,1><<<dim3(11, gy), blk, 0, stream>>>(inv_tp, tWg_p, bg_p, gp, nullptr,
            1408, 1408, 0.f, nullptr, nullptr, 0);
        tp_kernel<<<dim3((int)(Nc / 2)), blk, 0, stream>>>(xl, xr, tp_w, gp, inv_tp,
            tpg0, tpg1, tpg2, w3j, 1, (int)Nc);

        // ---- linear_p + fii -> out ----
        mgemm<2,1><<<dim3(1, gy),   blk, 0, stream>>>(tpg0, tWp0, nullptr, nullptr, nullptr,
            128, 384, s384, fc, oc, 0);
        mgemm<2,3><<<dim3(1, 3*gy), blk, 0, stream>>>(tpg1, tWp1, nullptr, nullptr, nullptr,
            128, 512, s512, fc, oc, 128);
        mgemm<2,5><<<dim3(1, 5*gy), blk, 0, stream>>>(tpg2, tWp2, nullptr, nullptr, nullptr,
            128, 512, s512, fc, oc, 512);
    }
}

// Round 5
// 605.631 us; speedup vs baseline: 5.4956x; 1.4350x over previous
//
#include <hip/hip_runtime.h>
#include <hip/hip_bf16.h>
#include <cmath>
#include <complex>
#include <algorithm>

typedef __hip_bfloat16 bf16;
typedef __bf16 bf16x8 __attribute__((ext_vector_type(8)));
typedef float f32x4 __attribute__((ext_vector_type(4)));

#define NN 16384

constexpr int P_L1[11] = {0,0,0,1,1,1,1,2,2,2,2};
constexpr int P_L2[11] = {0,1,2,0,1,1,2,0,1,2,2};
constexpr int P_LO[11] = {0,1,2,1,0,2,1,2,1,0,2};
constexpr int P_OFF[11]= {0,1,10,35,44,53,98,143,168,213,238}; // sizes 1,9,25,9,9,45,45,25,45,25,125 -> 363
constexpr int P_G[11]  = {0,0,0,1,1,1,2,2,3,2,3};

struct W3JPack { float v[363]; };

// ---------------------------------------------------------------------------
// invariants of x -> bf16 [Nc][384]
// ---------------------------------------------------------------------------
__global__ __launch_bounds__(256) void invx_kernel(const float* __restrict__ x,
                                                   bf16* __restrict__ inv_x)
{
    int idx = blockIdx.x * 256 + threadIdx.x;
    int n = idx / 384, c = idx - n * 384;
    const float* p = x + (size_t)n * 1152;
    float v;
    if (c < 128) {
        v = p[c];
    } else if (c < 256) {
        const float* q = p + 128 + (c - 128) * 3;
        v = sqrtf(q[0]*q[0] + q[1]*q[1] + q[2]*q[2]);
    } else {
        const float* q = p + 512 + (c - 256) * 5;
        v = sqrtf(q[0]*q[0] + q[1]*q[1] + q[2]*q[2] + q[3]*q[3] + q[4]*q[4]);
    }
    inv_x[idx] = __float2bfloat16(v);
}

// ---------------------------------------------------------------------------
// batched weight convert+transpose: W f32 [K][Nn] -> Bt bf16 [Nn][K]
// ---------------------------------------------------------------------------
struct WPack {
    const float* W[12];
    bf16* Bt[12];
    int K[12];
    int Nn[12];
};

__global__ __launch_bounds__(256) void wconv_all(WPack wp)
{
    __shared__ float t[32][33];
    int z = blockIdx.z;
    int K = wp.K[z], Nn = wp.Nn[z];
    int bx = blockIdx.x * 32;  // n tile
    int by = blockIdx.y * 32;  // k tile
    if (bx >= Nn || by >= K) return;
    const float* W = wp.W[z];
    bf16* Bt = wp.Bt[z];
    int lx = threadIdx.x & 31, ly = threadIdx.x >> 5;
    #pragma unroll
    for (int yy = ly; yy < 32; yy += 8)
        t[yy][lx] = W[(size_t)(by + yy) * Nn + bx + lx];
    __syncthreads();
    #pragma unroll
    for (int yy = ly; yy < 32; yy += 8)
        Bt[(size_t)(bx + yy) * K + by + lx] = __float2bfloat16(t[lx][yy]);
}

// ---------------------------------------------------------------------------
// fused gated-x materialize for BOTH sides: reads gbuf [Nc][768] bf16
// xg[(n,i)][u] regions: l0 @0 [Nc][128]; l1 @Nc*128; l2 @Nc*512 (elem offsets)
// ---------------------------------------------------------------------------
__global__ __launch_bounds__(256) void gate_apply2(const float* __restrict__ x,
                                                   const bf16* __restrict__ gbuf,
                                                   bf16* __restrict__ xg_l,
                                                   bf16* __restrict__ xg_r, int Nc)
{
    int idx = blockIdx.x * 256 + threadIdx.x;
    int n = idx >> 7, u = idx & 127;
    const float* xrow = x + (size_t)n * 1152;
    const bf16* grow = gbuf + (size_t)n * 768;
    size_t O1 = (size_t)Nc * 128, O2 = (size_t)Nc * 512;
    float gl0 = __bfloat162float(grow[u]);
    float gl1 = __bfloat162float(grow[128 + u]);
    float gl2 = __bfloat162float(grow[256 + u]);
    float gr0 = __bfloat162float(grow[384 + u]);
    float gr1 = __bfloat162float(grow[512 + u]);
    float gr2 = __bfloat162float(grow[640 + u]);
    float x0 = xrow[u];
    xg_l[(size_t)n * 128 + u] = __float2bfloat16(x0 * gl0);
    xg_r[(size_t)n * 128 + u] = __float2bfloat16(x0 * gr0);
    #pragma unroll
    for (int i = 0; i < 3; ++i) {
        float xv = xrow[128 + u * 3 + i];
        xg_l[O1 + ((size_t)n * 3 + i) * 128 + u] = __float2bfloat16(xv * gl1);
        xg_r[O1 + ((size_t)n * 3 + i) * 128 + u] = __float2bfloat16(xv * gr1);
    }
    #pragma unroll
    for (int i = 0; i < 5; ++i) {
        float xv = xrow[512 + u * 5 + i];
        xg_l[O2 + ((size_t)n * 5 + i) * 128 + u] = __float2bfloat16(xv * gl2);
        xg_r[O2 + ((size_t)n * 5 + i) * 128 + u] = __float2bfloat16(xv * gr2);
    }
}

// ---------------------------------------------------------------------------
// shared MFMA GEMM core: 128x128 tile, BK=64, 4 waves 2x2, 4x4 16x16x32 frags
// global_load_lds staging, XOR-swizzled LDS (byte ^= (row&7)<<4)
// ---------------------------------------------------------------------------
__device__ __forceinline__ void gemm_core(
    const bf16* __restrict__ A, const bf16* __restrict__ Bt, int K,
    int bm, int bn, int lane, int wid, char* AsB, char* BsB,
    const int* srow, const int* scol, f32x4 acc[4][4])
{
    const int wm = (wid >> 1) * 64;
    const int wn = (wid & 1) * 64;
    for (int k0 = 0; k0 < K; k0 += 64) {
        #pragma unroll
        for (int q = 0; q < 4; ++q) {
            const bf16* ga = A + (size_t)(bm + srow[q]) * K + k0 + scol[q];
            __builtin_amdgcn_global_load_lds(
                (const __attribute__((address_space(1))) void*)ga,
                (__attribute__((address_space(3))) void*)(AsB + wid * 4096 + q * 1024),
                16, 0, 0);
            const bf16* gb = Bt + (size_t)(bn + srow[q]) * K + k0 + scol[q];
            __builtin_amdgcn_global_load_lds(
                (const __attribute__((address_space(1))) void*)gb,
                (__attribute__((address_space(3))) void*)(BsB + wid * 4096 + q * 1024),
                16, 0, 0);
        }
        asm volatile("s_waitcnt vmcnt(0)" ::: "memory");
        __syncthreads();
        #pragma unroll
        for (int kh = 0; kh < 2; ++kh) {
            bf16x8 av[4], bv[4];
            #pragma unroll
            for (int m = 0; m < 4; ++m) {
                int row = wm + m * 16 + (lane & 15);
                int off = row * 128 + kh * 64 + ((lane >> 4) << 4);
                off ^= (row & 7) << 4;
                av[m] = *reinterpret_cast<const bf16x8*>(AsB + off);
            }
            #pragma unroll
            for (int n = 0; n < 4; ++n) {
                int row = wn + n * 16 + (lane & 15);
                int off = row * 128 + kh * 64 + ((lane >> 4) << 4);
                off ^= (row & 7) << 4;
                bv[n] = *reinterpret_cast<const bf16x8*>(BsB + off);
            }
            #pragma unroll
            for (int m = 0; m < 4; ++m)
                #pragma unroll
                for (int n = 0; n < 4; ++n)
                    acc[m][n] = __builtin_amdgcn_mfma_f32_16x16x32_bf16(av[m], bv[n], acc[m][n], 0, 0, 0);
        }
        __syncthreads();
    }
}

__device__ __forceinline__ void stage_coords(int lane, int wid, int* srow, int* scol)
{
    #pragma unroll
    for (int q = 0; q < 4; ++q) {
        int d = wid * 4096 + q * 1024 + lane * 16;
        int row = d >> 7;
        int colb = (d & 127) ^ ((row & 7) << 4);
        srow[q] = row;
        scol[q] = colb >> 1;
    }
}

// ---------------------------------------------------------------------------
// mgemm: gate GEMMs (K2 fused l+r, K5). EPI: silu(acc + bias) -> bf16.
// XCD-bijective swizzle: same-XCD blocks share M-panels (A fetched once/HBM).
// ---------------------------------------------------------------------------
__global__ __launch_bounds__(256) void mgemm(
    const bf16* __restrict__ A, const bf16* __restrict__ Bt,
    const float* __restrict__ bias, const float* __restrict__ bias2, int split,
    bf16* __restrict__ C, int Nn, int K)
{
    __shared__ __align__(16) char Lds[32768];
    char* AsB = Lds;
    char* BsB = Lds + 16384;
    const int tid = threadIdx.x;
    const int lane = tid & 63;
    const int wid = tid >> 6;

    // bijective XCD swizzle (m204), n-fastest decomposition
    int nwg = gridDim.x * gridDim.y;
    int orig = blockIdx.y * gridDim.x + blockIdx.x;
    int q8 = nwg >> 3, r8 = nwg & 7;
    int xcd = orig & 7, pos = orig >> 3;
    int t = (xcd < r8 ? xcd * (q8 + 1) : r8 * (q8 + 1) + (xcd - r8) * q8) + pos;
    const int bm = (t / gridDim.x) * 128;
    const int bn = (t % gridDim.x) * 128;

    int srow[4], scol[4];
    stage_coords(lane, wid, srow, scol);

    f32x4 acc[4][4];
    #pragma unroll
    for (int m = 0; m < 4; ++m)
        #pragma unroll
        for (int n = 0; n < 4; ++n)
            acc[m][n] = (f32x4){0.f, 0.f, 0.f, 0.f};

    gemm_core(A, Bt, K, bm, bn, lane, wid, AsB, BsB, srow, scol, acc);

    const int wm = (wid >> 1) * 64;
    const int wn = (wid & 1) * 64;
    #pragma unroll
    for (int m = 0; m < 4; ++m) {
        int row0 = bm + wm + m * 16 + ((lane >> 4) << 2);
        #pragma unroll
        for (int n = 0; n < 4; ++n) {
            int col = bn + wn + n * 16 + (lane & 15);
            float b = (col < split) ? bias[col] : bias2[col - split];
            #pragma unroll
            for (int r = 0; r < 4; ++r) {
                float z = acc[m][n][r] + b;
                z = z / (1.f + __expf(-z));
                C[(size_t)(row0 + r) * Nn + col] = __float2bfloat16(z);
            }
        }
    }
}

// ---------------------------------------------------------------------------
// segmented MFMA GEMM (N=128 per segment, gridDim.x==1).
// EPI 1: acc*scale (+bias[col]) -> bf16 out[row*128+col]
// EPI 2: acc*scale + fii[oidx] -> f32 at n*1152+ooff+col*span+i (row=(n,i))
// ---------------------------------------------------------------------------
struct SegPack {
    const bf16* A[6];
    const bf16* Bt[6];
    const float* bias[6];
    bf16* out[6];
    float scale[6];
    int K[6];
    int segEnd[6];   // cumulative 128-row block count
    int ooff[6];
    int span[6];
};

template<int EPI>
__global__ __launch_bounds__(256) void mgemm_seg(
    SegPack sp, const float* __restrict__ fii, float* __restrict__ outf)
{
    __shared__ __align__(16) char Lds[32768];
    char* AsB = Lds;
    char* BsB = Lds + 16384;
    const int tid = threadIdx.x;
    const int lane = tid & 63;
    const int wid = tid >> 6;

    int by = blockIdx.y;
    int s = 0;
    while (by >= sp.segEnd[s]) ++s;
    int prev = s ? sp.segEnd[s - 1] : 0;
    const int bm = (by - prev) * 128;
    const bf16* A = sp.A[s];
    const bf16* Bt = sp.Bt[s];
    const int K = sp.K[s];
    const float scale = sp.scale[s];

    int srow[4], scol[4];
    stage_coords(lane, wid, srow, scol);

    f32x4 acc[4][4];
    #pragma unroll
    for (int m = 0; m < 4; ++m)
        #pragma unroll
        for (int n = 0; n < 4; ++n)
            acc[m][n] = (f32x4){0.f, 0.f, 0.f, 0.f};

    gemm_core(A, Bt, K, bm, 0, lane, wid, AsB, BsB, srow, scol, acc);

    const int wm = (wid >> 1) * 64;
    const int wn = (wid & 1) * 64;
    if (EPI == 1) {
        const float* bias = sp.bias[s];
        bf16* out = sp.out[s];
        #pragma unroll
        for (int m = 0; m < 4; ++m) {
            int row0 = bm + wm + m * 16 + ((lane >> 4) << 2);
            #pragma unroll
            for (int n = 0; n < 4; ++n) {
                int col = wn + n * 16 + (lane & 15);
                float b = bias ? bias[col] : 0.f;
                #pragma unroll
                for (int r = 0; r < 4; ++r) {
                    float z = acc[m][n][r] * scale + b;
                    out[(size_t)(row0 + r) * 128 + col] = __float2bfloat16(z);
                }
            }
        }
    } else {
        const int span = sp.span[s];
        const int ooff = sp.ooff[s];
        #pragma unroll
        for (int m = 0; m < 4; ++m) {
            int row0 = bm + wm + m * 16 + ((lane >> 4) << 2);
            #pragma unroll
            for (int n = 0; n < 4; ++n) {
                int col = wn + n * 16 + (lane & 15);
                #pragma unroll
                for (int r = 0; r < 4; ++r) {
                    int row = row0 + r;
                    int nn = row / span, i = row - nn * span;
                    size_t oidx = (size_t)nn * 1152 + ooff + (size_t)col * span + i;
                    outf[oidx] = acc[m][n][r] * scale + fii[oidx];
                }
            }
        }
    }
}

// ---------------------------------------------------------------------------
// TP kernel: thread=(n,u). phase 0: invariants bf16 [Nc][1408];
// phase 1: apply gate gp (bf16), write grouped i-major tpg (bf16).
// ---------------------------------------------------------------------------
__global__ __launch_bounds__(256) void tp_kernel(
    const bf16* __restrict__ xl, const bf16* __restrict__ xr,
    const float* __restrict__ tp_w, const bf16* __restrict__ gp,
    bf16* __restrict__ inv_tp,
    bf16* __restrict__ tpg0, bf16* __restrict__ tpg1, bf16* __restrict__ tpg2,
    W3JPack w3j, int phase, int Nc)
{
    int idx = blockIdx.x * 256 + threadIdx.x;
    int n = idx >> 7, u = idx & 127;
    const size_t O1 = (size_t)Nc * 128, O2 = (size_t)Nc * 512;
    float XL[3][5], XR[3][5];
    XL[0][0] = __bfloat162float(xl[(size_t)n * 128 + u]);
    XR[0][0] = __bfloat162float(xr[(size_t)n * 128 + u]);
    #pragma unroll
    for (int i = 0; i < 3; ++i) {
        XL[1][i] = __bfloat162float(xl[O1 + ((size_t)n * 3 + i) * 128 + u]);
        XR[1][i] = __bfloat162float(xr[O1 + ((size_t)n * 3 + i) * 128 + u]);
    }
    #pragma unroll
    for (int i = 0; i < 5; ++i) {
        XL[2][i] = __bfloat162float(xl[O2 + ((size_t)n * 5 + i) * 128 + u]);
        XR[2][i] = __bfloat162float(xr[O2 + ((size_t)n * 5 + i) * 128 + u]);
    }
    const float SQF[3] = {1.f, 1.7320508075688772f, 2.2360679774997896f};
    #pragma unroll
    for (int p = 0; p < 11; ++p) {
        const int l1 = P_L1[p], l2 = P_L2[p], lo = P_LO[p];
        const int d1 = 2*l1+1, d2 = 2*l2+1, dd = 2*lo+1;
        const float* W = &w3j.v[P_OFF[p]];
        float tw = tp_w[p * 128 + u] * SQF[lo];
        float o[5];
        #pragma unroll
        for (int k = 0; k < dd; ++k) {
            float a = 0.f;
            #pragma unroll
            for (int i = 0; i < d1; ++i)
                #pragma unroll
                for (int jj = 0; jj < d2; ++jj)
                    a += W[(i * d2 + jj) * dd + k] * XL[l1][i] * XR[l2][jj];
            o[k] = a * tw;
        }
        if (phase == 0) {
            float iv;
            if (lo == 0) iv = o[0];
            else {
                float s = 0.f;
                #pragma unroll
                for (int k = 0; k < dd; ++k) s += o[k] * o[k];
                iv = sqrtf(s);
            }
            inv_tp[(size_t)n * 1408 + p * 128 + u] = __float2bfloat16(iv);
        } else {
            float g = __bfloat162float(gp[(size_t)n * 1408 + p * 128 + u]);
            int gg = P_G[p];
            if (lo == 0) {
                tpg0[(size_t)n * 384 + gg * 128 + u] = __float2bfloat16(o[0] * g);
            } else if (lo == 1) {
                #pragma unroll
                for (int k = 0; k < 3; ++k)
                    tpg1[((size_t)n * 3 + k) * 512 + gg * 128 + u] = __float2bfloat16(o[k] * g);
            } else {
                #pragma unroll
                for (int k = 0; k < 5; ++k)
                    tpg2[((size_t)n * 5 + k) * 512 + gg * 128 + u] = __float2bfloat16(o[k] * g);
            }
        }
    }
}

// ---------------------------------------------------------------------------
// Host: real-basis Wigner 3j (exact port of the reference math)
// ---------------------------------------------------------------------------
static double factd(int n) {
    static const double F[10] = {1,1,2,6,24,120,720,5040,40320,362880};
    return F[n];
}

static double su2_cg(int j1,int m1,int j2,int m2,int j3,int m3){
    if (m3 != m1 + m2) return 0.0;
    int vmin = std::max(std::max(-j1 + j2 + m3, -j1 + m1), 0);
    int vmax = std::min(std::min(j2 + j3 + m1, j3 - j1 + j2), j3 + m3);
    if (vmax < vmin) return 0.0;
    double c = std::sqrt((2*j3+1) * factd(j3+j1-j2) * factd(j3-j1+j2) * factd(j1+j2-j3)
               * factd(j3+m3) * factd(j3-m3)
               / (factd(j1+j2+j3+1) * factd(j1-m1) * factd(j1+m1) * factd(j2-m2) * factd(j2+m2)));
    double s = 0.0;
    for (int v = vmin; v <= vmax; ++v) {
        double sg = ((v + j2 + m2) & 1) ? -1.0 : 1.0;
        s += sg * factd(j2+j3+m1-v) * factd(j1-m1+v)
             / (factd(v) * factd(j3-j1+j2-v) * factd(j3+m3-v) * factd(v+j1-j2-m3));
    }
    return c * s;
}

typedef std::complex<double> cd;

static void q_matrix(int l, cd* q) {
    int d = 2*l+1;
    for (int i = 0; i < d*d; ++i) q[i] = cd(0,0);
    const double is2 = 1.0 / std::sqrt(2.0);
    for (int m = -l; m < 0; ++m) {
        q[(l+m)*d + (l-m)] = cd(is2, 0);
        q[(l+m)*d + (l+m)] = cd(0, -is2);
    }
    q[l*d + l] = cd(1,0);
    for (int m = 1; m <= l; ++m) {
        double sg = (m & 1) ? -1.0 : 1.0;
        q[(l+m)*d + (l+m)] = cd(sg*is2, 0);
        q[(l+m)*d + (l-m)] = cd(0, sg*is2);
    }
    cd f = (l==0) ? cd(1,0) : (l==1) ? cd(0,-1) : cd(-1,0);
    for (int i = 0; i < d*d; ++i) q[i] *= f;
}

static void compute_w3j(float* out) {
    for (int p = 0; p < 11; ++p) {
        int l1 = P_L1[p], l2 = P_L2[p], l3 = P_LO[p];
        int d1 = 2*l1+1, d2 = 2*l2+1, d3 = 2*l3+1;
        cd q1[25], q2[25], q3[25];
        q_matrix(l1, q1); q_matrix(l2, q2); q_matrix(l3, q3);
        double nrm = std::sqrt((double)d3);
        for (int a = 0; a < d1; ++a)
        for (int b = 0; b < d2; ++b)
        for (int c = 0; c < d3; ++c) {
            cd s(0,0);
            for (int i = 0; i < d1; ++i)
            for (int k = 0; k < d2; ++k)
            for (int m = 0; m < d3; ++m) {
                double cg = su2_cg(l1, i-l1, l2, k-l2, l3, m-l3);
                if (cg == 0.0) continue;
                s += q1[i*d1 + a] * q2[k*d2 + b] * std::conj(q3[m*d3 + c]) * cg;
            }
            out[P_OFF[p] + (a*d2 + b)*d3 + c] = (float)(s.real() / nrm);
        }
    }
}

// ---------------------------------------------------------------------------
extern "C" void kernel_launch(void* const* d_in, const int* in_sizes, int n_in,
                              void* d_out, int out_size, void* d_ws, size_t ws_size,
                              hipStream_t stream)
{
    (void)in_sizes; (void)n_in; (void)out_size;
    const float* x    = (const float*)d_in[0];
    const float* fii  = (const float*)d_in[1];
    const float* Wg_l = (const float*)d_in[2];
    const float* bg_l = (const float*)d_in[3];
    const float* Wl0  = (const float*)d_in[4];
    const float* Wl1  = (const float*)d_in[5];
    const float* Wl2  = (const float*)d_in[6];
    const float* bl0  = (const float*)d_in[7];
    const float* Wg_r = (const float*)d_in[8];
    const float* bg_r = (const float*)d_in[9];
    const float* Wr0  = (const float*)d_in[10];
    const float* Wr1  = (const float*)d_in[11];
    const float* Wr2  = (const float*)d_in[12];
    const float* br0  = (const float*)d_in[13];
    const float* tp_w = (const float*)d_in[14];
    const float* Wg_p = (const float*)d_in[15];
    const float* bg_p = (const float*)d_in[16];
    const float* Wp0  = (const float*)d_in[17];
    const float* Wp1  = (const float*)d_in[18];
    const float* Wp2  = (const float*)d_in[19];
    float* out = (float*)d_out;

    W3JPack w3j;
    compute_w3j(w3j.v);

    auto al = [](size_t b) { return (b + 255) & ~(size_t)255; };
    char* base = (char*)d_ws;
    size_t woff = 0;
    auto walloc = [&](size_t elems) { void* p = base + woff; woff += al(elems * 2); return (bf16*)p; };
    bf16* tWg   = walloc((size_t)768 * 384);      // [Wg_l | Wg_r] transposed
    bf16* tWl0  = walloc(128 * 128);
    bf16* tWl1  = walloc(128 * 128);
    bf16* tWl2  = walloc(128 * 128);
    bf16* tWr0  = walloc(128 * 128);
    bf16* tWr1  = walloc(128 * 128);
    bf16* tWr2  = walloc(128 * 128);
    bf16* tWg_p = walloc((size_t)1408 * 1408);
    bf16* tWp0  = walloc(128 * 384);
    bf16* tWp1  = walloc(128 * 512);
    bf16* tWp2  = walloc(128 * 512);
    const size_t wtotal = woff;

    // per-node bytes: xl 2304 + xr 2304 + R3 11776 = 16384
    int c = 1; size_t Nc;
    for (;; c *= 2) {
        Nc = NN / c;
        size_t tot = wtotal + 2 * al(Nc * 2304) + al(Nc * 11776);
        if (tot <= ws_size || c >= 32) break;
    }
    char* cb = base + wtotal;
    bf16* xl = (bf16*)cb;  cb += al(Nc * 2304);
    bf16* xr = (bf16*)cb;  cb += al(Nc * 2304);
    char* R3 = cb;
    // t1
    bf16* inv_x = (bf16*)R3;                    // [0, 768Nc)
    bf16* gbuf  = (bf16*)(R3 + Nc * 768);       // [768Nc, 2304Nc)  [Nc][768]
    bf16* xg_l  = (bf16*)(R3 + Nc * 2304);      // [2304Nc, 4608Nc)
    bf16* xg_r  = (bf16*)(R3 + Nc * 4608);      // [4608Nc, 6912Nc)
    // t2/t3
    bf16* inv_tp = (bf16*)R3;                   // [0, 2816Nc)
    bf16* tpg0   = (bf16*)R3;                   // [0, 768Nc)
    bf16* tpg1   = (bf16*)(R3 + Nc * 768);      // [768Nc, 3840Nc)
    bf16* tpg2   = (bf16*)(R3 + Nc * 3840);     // [3840Nc, 8960Nc)
    bf16* gp     = (bf16*)(R3 + Nc * 8960);     // [8960Nc, 11776Nc)

    const float s128 = 0.08838834764831845f;   // 1/sqrt(128)
    const float s384 = 0.05103103630798287f;   // 1/sqrt(384)
    const float s512 = 0.044194173824159216f;  // 1/sqrt(512)
    dim3 blk(256);

    // batched weight convert+transpose (once)
    WPack wp;
    wp.W[0] = Wg_l; wp.Bt[0] = tWg;             wp.K[0] = 384;  wp.Nn[0] = 384;
    wp.W[1] = Wg_r; wp.Bt[1] = tWg + 384*384;   wp.K[1] = 384;  wp.Nn[1] = 384;
    wp.W[2] = Wl0;  wp.Bt[2] = tWl0;            wp.K[2] = 128;  wp.Nn[2] = 128;
    wp.W[3] = Wl1;  wp.Bt[3] = tWl1;            wp.K[3] = 128;  wp.Nn[3] = 128;
    wp.W[4] = Wl2;  wp.Bt[4] = tWl2;            wp.K[4] = 128;  wp.Nn[4] = 128;
    wp.W[5] = Wr0;  wp.Bt[5] = tWr0;            wp.K[5] = 128;  wp.Nn[5] = 128;
    wp.W[6] = Wr1;  wp.Bt[6] = tWr1;            wp.K[6] = 128;  wp.Nn[6] = 128;
    wp.W[7] = Wr2;  wp.Bt[7] = tWr2;            wp.K[7] = 128;  wp.Nn[7] = 128;
    wp.W[8] = Wg_p; wp.Bt[8] = tWg_p;           wp.K[8] = 1408; wp.Nn[8] = 1408;
    wp.W[9] = Wp0;  wp.Bt[9] = tWp0;            wp.K[9] = 384;  wp.Nn[9] = 128;
    wp.W[10]= Wp1;  wp.Bt[10]= tWp1;            wp.K[10]= 512;  wp.Nn[10]= 128;
    wp.W[11]= Wp2;  wp.Bt[11]= tWp2;            wp.K[11]= 512;  wp.Nn[11]= 128;
    wconv_all<<<dim3(44, 44, 12), blk, 0, stream>>>(wp);

    const int gy = (int)(Nc / 128);
    for (int ch = 0; ch < c; ++ch) {
        const float* xc = x   + (size_t)ch * Nc * 1152;
        const float* fc = fii + (size_t)ch * Nc * 1152;
        float*       oc = out + (size_t)ch * Nc * 1152;

        invx_kernel<<<dim3((int)(Nc * 384 / 256)), blk, 0, stream>>>(xc, inv_x);

        // K2 fused l+r: gbuf = silu(inv_x @ [Wg_l|Wg_r] + [bg_l|bg_r])
        mgemm<<<dim3(6, gy), blk, 0, stream>>>(inv_x, tWg, bg_l, bg_r, 384,
                                               gbuf, 768, 384);

        // gated-x for both sides
        gate_apply2<<<dim3((int)(Nc / 2)), blk, 0, stream>>>(xc, gbuf, xg_l, xg_r, (int)Nc);

        // K3 batched: 6 segments (l0/l1/l2 x l/r), all N=128 K=128
        {
            SegPack sp{};
            const bf16* As[6]  = {xg_l, xg_l + Nc*128, xg_l + Nc*512,
                                  xg_r, xg_r + Nc*128, xg_r + Nc*512};
            const bf16* Bs[6]  = {tWl0, tWl1, tWl2, tWr0, tWr1, tWr2};
            const float* bi[6] = {bl0, nullptr, nullptr, br0, nullptr, nullptr};
            bf16* os[6]        = {xl, xl + Nc*128, xl + Nc*512,
                                  xr, xr + Nc*128, xr + Nc*512};
            int rows[6] = {gy, 3*gy, 5*gy, gy, 3*gy, 5*gy};
            int acc_r = 0;
            for (int s = 0; s < 6; ++s) {
                sp.A[s] = As[s]; sp.Bt[s] = Bs[s]; sp.bias[s] = bi[s]; sp.out[s] = os[s];
                sp.scale[s] = s128; sp.K[s] = 128;
                acc_r += rows[s]; sp.segEnd[s] = acc_r;
                sp.ooff[s] = 0; sp.span[s] = 1;
            }
            mgemm_seg<1><<<dim3(1, 18*gy), blk, 0, stream>>>(sp, nullptr, nullptr);
        }

        // TP invariants
        tp_kernel<<<dim3((int)(Nc / 2)), blk, 0, stream>>>(xl, xr, tp_w, gp, inv_tp,
            tpg0, tpg1, tpg2, w3j, 0, (int)Nc);

        // K5: gp = silu(inv_tp @ Wg_p + bg_p)  (bf16 out)
        mgemm<<<dim3(11, gy), blk, 0, stream>>>(inv_tp, tWg_p, bg_p, nullptr, 1408,
                                                gp, 1408, 1408);

        // TP recompute + gate apply
        tp_kernel<<<dim3((int)(Nc / 2)), blk, 0, stream>>>(xl, xr, tp_w, gp, inv_tp,
            tpg0, tpg1, tpg2, w3j, 1, (int)Nc);

        // K6 batched: 3 segments -> out (+fii), e3nn layout
        {
            SegPack sp{};
            sp.A[0] = tpg0; sp.Bt[0] = tWp0; sp.K[0] = 384; sp.scale[0] = s384;
            sp.segEnd[0] = gy;      sp.ooff[0] = 0;   sp.span[0] = 1;
            sp.A[1] = tpg1; sp.Bt[1] = tWp1; sp.K[1] = 512; sp.scale[1] = s512;
            sp.segEnd[1] = 4*gy;    sp.ooff[1] = 128; sp.span[1] = 3;
            sp.A[2] = tpg2; sp.Bt[2] = tWp2; sp.K[2] = 512; sp.scale[2] = s512;
            sp.segEnd[2] = 9*gy;    sp.ooff[2] = 512; sp.span[2] = 5;
            for (int s = 3; s < 6; ++s) sp.segEnd[s] = 9*gy + 1 + s; // unreachable
            mgemm_seg<2><<<dim3(1, 9*gy), blk, 0, stream>>>(sp, fc, oc);
        }
    }
}

// Round 6
// 559.512 us; speedup vs baseline: 5.9486x; 1.0824x over previous
//
#include <hip/hip_runtime.h>
#include <hip/hip_bf16.h>
#include <cmath>
#include <complex>
#include <algorithm>

typedef __hip_bfloat16 bf16;
typedef __bf16 bf16x8 __attribute__((ext_vector_type(8)));
typedef float f32x4 __attribute__((ext_vector_type(4)));

#define NN 16384

constexpr int P_L1[11] = {0,0,0,1,1,1,1,2,2,2,2};
constexpr int P_L2[11] = {0,1,2,0,1,1,2,0,1,2,2};
constexpr int P_LO[11] = {0,1,2,1,0,2,1,2,1,0,2};
constexpr int P_OFF[11]= {0,1,10,35,44,53,98,143,168,213,238}; // sizes 1,9,25,9,9,45,45,25,45,25,125 -> 363
constexpr int P_G[11]  = {0,0,0,1,1,1,2,2,3,2,3};

struct W3JPack { float v[363]; };

// ---------------------------------------------------------------------------
// invariants of x -> bf16 [Nc][384]
// ---------------------------------------------------------------------------
__global__ __launch_bounds__(256) void invx_kernel(const float* __restrict__ x,
                                                   bf16* __restrict__ inv_x)
{
    int idx = blockIdx.x * 256 + threadIdx.x;
    int n = idx / 384, c = idx - n * 384;
    const float* p = x + (size_t)n * 1152;
    float v;
    if (c < 128) {
        v = p[c];
    } else if (c < 256) {
        const float* q = p + 128 + (c - 128) * 3;
        v = sqrtf(q[0]*q[0] + q[1]*q[1] + q[2]*q[2]);
    } else {
        const float* q = p + 512 + (c - 256) * 5;
        v = sqrtf(q[0]*q[0] + q[1]*q[1] + q[2]*q[2] + q[3]*q[3] + q[4]*q[4]);
    }
    inv_x[idx] = __float2bfloat16(v);
}

// ---------------------------------------------------------------------------
// batched weight convert+transpose: W f32 [K][Nn] -> Bt bf16 [Nn][K]
// ---------------------------------------------------------------------------
struct WPack {
    const float* W[12];
    bf16* Bt[12];
    int K[12];
    int Nn[12];
};

__global__ __launch_bounds__(256) void wconv_all(WPack wp)
{
    __shared__ float t[32][33];
    int z = blockIdx.z;
    int K = wp.K[z], Nn = wp.Nn[z];
    int bx = blockIdx.x * 32;  // n tile
    int by = blockIdx.y * 32;  // k tile
    if (bx >= Nn || by >= K) return;
    const float* W = wp.W[z];
    bf16* Bt = wp.Bt[z];
    int lx = threadIdx.x & 31, ly = threadIdx.x >> 5;
    #pragma unroll
    for (int yy = ly; yy < 32; yy += 8)
        t[yy][lx] = W[(size_t)(by + yy) * Nn + bx + lx];
    __syncthreads();
    #pragma unroll
    for (int yy = ly; yy < 32; yy += 8)
        Bt[(size_t)(bx + yy) * K + by + lx] = __float2bfloat16(t[lx][yy]);
}

// ---------------------------------------------------------------------------
// fused gated-x materialize for BOTH sides: reads gbuf [Nc][768] bf16
// xg[(n,i)][u] regions: l0 @0 [Nc][128]; l1 @Nc*128; l2 @Nc*512 (elem offsets)
// ---------------------------------------------------------------------------
__global__ __launch_bounds__(256) void gate_apply2(const float* __restrict__ x,
                                                   const bf16* __restrict__ gbuf,
                                                   bf16* __restrict__ xg_l,
                                                   bf16* __restrict__ xg_r, int Nc)
{
    int idx = blockIdx.x * 256 + threadIdx.x;
    int n = idx >> 7, u = idx & 127;
    const float* xrow = x + (size_t)n * 1152;
    const bf16* grow = gbuf + (size_t)n * 768;
    size_t O1 = (size_t)Nc * 128, O2 = (size_t)Nc * 512;
    float gl0 = __bfloat162float(grow[u]);
    float gl1 = __bfloat162float(grow[128 + u]);
    float gl2 = __bfloat162float(grow[256 + u]);
    float gr0 = __bfloat162float(grow[384 + u]);
    float gr1 = __bfloat162float(grow[512 + u]);
    float gr2 = __bfloat162float(grow[640 + u]);
    float x0 = xrow[u];
    xg_l[(size_t)n * 128 + u] = __float2bfloat16(x0 * gl0);
    xg_r[(size_t)n * 128 + u] = __float2bfloat16(x0 * gr0);
    #pragma unroll
    for (int i = 0; i < 3; ++i) {
        float xv = xrow[128 + u * 3 + i];
        xg_l[O1 + ((size_t)n * 3 + i) * 128 + u] = __float2bfloat16(xv * gl1);
        xg_r[O1 + ((size_t)n * 3 + i) * 128 + u] = __float2bfloat16(xv * gr1);
    }
    #pragma unroll
    for (int i = 0; i < 5; ++i) {
        float xv = xrow[512 + u * 5 + i];
        xg_l[O2 + ((size_t)n * 5 + i) * 128 + u] = __float2bfloat16(xv * gl2);
        xg_r[O2 + ((size_t)n * 5 + i) * 128 + u] = __float2bfloat16(xv * gr2);
    }
}

// ---------------------------------------------------------------------------
// shared MFMA GEMM core: 128x128 tile, BK=64, 4 waves 2x2, 4x4 16x16x32 frags
// DOUBLE-BUFFERED LDS (2x32KB) + counted vmcnt(8) prefetch + raw s_barrier:
// tile t+1's global_load_lds stay in flight across barriers while t computes.
// XOR-swizzled LDS (byte ^= (row&7)<<4); per-wave lgkmcnt (compiler) before
// MFMA guarantees reads done before the trailing barrier -> restage is safe.
// ---------------------------------------------------------------------------
__device__ __forceinline__ void gemm_core(
    const bf16* __restrict__ A, const bf16* __restrict__ Bt, int K,
    int bm, int bn, int lane, int wid, char* AsB, char* BsB,
    const int* srow, const int* scol, f32x4 acc[4][4])
{
    const int wm = (wid >> 1) * 64;
    const int wn = (wid & 1) * 64;
    const int nsteps = K >> 6;

    auto stage = [&](int buf, int t) {
        int k0 = t << 6;
        #pragma unroll
        for (int q = 0; q < 4; ++q) {
            const bf16* ga = A + (size_t)(bm + srow[q]) * K + k0 + scol[q];
            __builtin_amdgcn_global_load_lds(
                (const __attribute__((address_space(1))) void*)ga,
                (__attribute__((address_space(3))) void*)(AsB + buf * 16384 + wid * 4096 + q * 1024),
                16, 0, 0);
            const bf16* gb = Bt + (size_t)(bn + srow[q]) * K + k0 + scol[q];
            __builtin_amdgcn_global_load_lds(
                (const __attribute__((address_space(1))) void*)gb,
                (__attribute__((address_space(3))) void*)(BsB + buf * 16384 + wid * 4096 + q * 1024),
                16, 0, 0);
        }
    };

    stage(0, 0);
    int cur = 0;
    for (int t = 0; t < nsteps; ++t) {
        if (t + 1 < nsteps) {
            stage(cur ^ 1, t + 1);                       // 8 newest loads in flight
            asm volatile("s_waitcnt vmcnt(8)" ::: "memory");  // wait only tile t's 8
        } else {
            asm volatile("s_waitcnt vmcnt(0)" ::: "memory");
        }
        __builtin_amdgcn_s_barrier();
        char* Ab = AsB + cur * 16384;
        char* Bb = BsB + cur * 16384;
        #pragma unroll
        for (int kh = 0; kh < 2; ++kh) {
            bf16x8 av[4], bv[4];
            #pragma unroll
            for (int m = 0; m < 4; ++m) {
                int row = wm + m * 16 + (lane & 15);
                int off = row * 128 + kh * 64 + ((lane >> 4) << 4);
                off ^= (row & 7) << 4;
                av[m] = *reinterpret_cast<const bf16x8*>(Ab + off);
            }
            #pragma unroll
            for (int n = 0; n < 4; ++n) {
                int row = wn + n * 16 + (lane & 15);
                int off = row * 128 + kh * 64 + ((lane >> 4) << 4);
                off ^= (row & 7) << 4;
                bv[n] = *reinterpret_cast<const bf16x8*>(Bb + off);
            }
            __builtin_amdgcn_s_setprio(1);
            #pragma unroll
            for (int m = 0; m < 4; ++m)
                #pragma unroll
                for (int n = 0; n < 4; ++n)
                    acc[m][n] = __builtin_amdgcn_mfma_f32_16x16x32_bf16(av[m], bv[n], acc[m][n], 0, 0, 0);
            __builtin_amdgcn_s_setprio(0);
        }
        __builtin_amdgcn_s_barrier();
        cur ^= 1;
    }
}

__device__ __forceinline__ void stage_coords(int lane, int wid, int* srow, int* scol)
{
    #pragma unroll
    for (int q = 0; q < 4; ++q) {
        int d = wid * 4096 + q * 1024 + lane * 16;
        int row = d >> 7;
        int colb = (d & 127) ^ ((row & 7) << 4);
        srow[q] = row;
        scol[q] = colb >> 1;
    }
}

// ---------------------------------------------------------------------------
// mgemm: gate GEMMs (K2 fused l+r, K5). EPI: silu(acc + bias) -> bf16.
// XCD-bijective swizzle: same-XCD blocks share M-panels (A fetched once/HBM).
// ---------------------------------------------------------------------------
__global__ __launch_bounds__(256) void mgemm(
    const bf16* __restrict__ A, const bf16* __restrict__ Bt,
    const float* __restrict__ bias, const float* __restrict__ bias2, int split,
    bf16* __restrict__ C, int Nn, int K)
{
    __shared__ __align__(16) char Lds[65536];
    char* AsB = Lds;
    char* BsB = Lds + 32768;
    const int tid = threadIdx.x;
    const int lane = tid & 63;
    const int wid = tid >> 6;

    // bijective XCD swizzle (m204), n-fastest decomposition
    int nwg = gridDim.x * gridDim.y;
    int orig = blockIdx.y * gridDim.x + blockIdx.x;
    int q8 = nwg >> 3, r8 = nwg & 7;
    int xcd = orig & 7, pos = orig >> 3;
    int t = (xcd < r8 ? xcd * (q8 + 1) : r8 * (q8 + 1) + (xcd - r8) * q8) + pos;
    const int bm = (t / gridDim.x) * 128;
    const int bn = (t % gridDim.x) * 128;

    int srow[4], scol[4];
    stage_coords(lane, wid, srow, scol);

    f32x4 acc[4][4];
    #pragma unroll
    for (int m = 0; m < 4; ++m)
        #pragma unroll
        for (int n = 0; n < 4; ++n)
            acc[m][n] = (f32x4){0.f, 0.f, 0.f, 0.f};

    gemm_core(A, Bt, K, bm, bn, lane, wid, AsB, BsB, srow, scol, acc);

    const int wm = (wid >> 1) * 64;
    const int wn = (wid & 1) * 64;
    #pragma unroll
    for (int m = 0; m < 4; ++m) {
        int row0 = bm + wm + m * 16 + ((lane >> 4) << 2);
        #pragma unroll
        for (int n = 0; n < 4; ++n) {
            int col = bn + wn + n * 16 + (lane & 15);
            float b = (col < split) ? bias[col] : bias2[col - split];
            #pragma unroll
            for (int r = 0; r < 4; ++r) {
                float z = acc[m][n][r] + b;
                z = z / (1.f + __expf(-z));
                C[(size_t)(row0 + r) * Nn + col] = __float2bfloat16(z);
            }
        }
    }
}

// ---------------------------------------------------------------------------
// segmented MFMA GEMM (N=128 per segment, gridDim.x==1).
// EPI 1: acc*scale (+bias[col]) -> bf16 out[row*128+col]
// EPI 2: acc*scale + fii[oidx] -> f32 at n*1152+ooff+col*span+i (row=(n,i))
// ---------------------------------------------------------------------------
struct SegPack {
    const bf16* A[6];
    const bf16* Bt[6];
    const float* bias[6];
    bf16* out[6];
    float scale[6];
    int K[6];
    int segEnd[6];   // cumulative 128-row block count
    int ooff[6];
    int span[6];
};

template<int EPI>
__global__ __launch_bounds__(256) void mgemm_seg(
    SegPack sp, const float* __restrict__ fii, float* __restrict__ outf)
{
    __shared__ __align__(16) char Lds[65536];
    char* AsB = Lds;
    char* BsB = Lds + 32768;
    const int tid = threadIdx.x;
    const int lane = tid & 63;
    const int wid = tid >> 6;

    int by = blockIdx.y;
    int s = 0;
    while (by >= sp.segEnd[s]) ++s;
    int prev = s ? sp.segEnd[s - 1] : 0;
    const int bm = (by - prev) * 128;
    const bf16* A = sp.A[s];
    const bf16* Bt = sp.Bt[s];
    const int K = sp.K[s];
    const float scale = sp.scale[s];

    int srow[4], scol[4];
    stage_coords(lane, wid, srow, scol);

    f32x4 acc[4][4];
    #pragma unroll
    for (int m = 0; m < 4; ++m)
        #pragma unroll
        for (int n = 0; n < 4; ++n)
            acc[m][n] = (f32x4){0.f, 0.f, 0.f, 0.f};

    gemm_core(A, Bt, K, bm, 0, lane, wid, AsB, BsB, srow, scol, acc);

    const int wm = (wid >> 1) * 64;
    const int wn = (wid & 1) * 64;
    if (EPI == 1) {
        const float* bias = sp.bias[s];
        bf16* out = sp.out[s];
        #pragma unroll
        for (int m = 0; m < 4; ++m) {
            int row0 = bm + wm + m * 16 + ((lane >> 4) << 2);
            #pragma unroll
            for (int n = 0; n < 4; ++n) {
                int col = wn + n * 16 + (lane & 15);
                float b = bias ? bias[col] : 0.f;
                #pragma unroll
                for (int r = 0; r < 4; ++r) {
                    float z = acc[m][n][r] * scale + b;
                    out[(size_t)(row0 + r) * 128 + col] = __float2bfloat16(z);
                }
            }
        }
    } else {
        const int span = sp.span[s];
        const int ooff = sp.ooff[s];
        #pragma unroll
        for (int m = 0; m < 4; ++m) {
            int row0 = bm + wm + m * 16 + ((lane >> 4) << 2);
            #pragma unroll
            for (int n = 0; n < 4; ++n) {
                int col = wn + n * 16 + (lane & 15);
                #pragma unroll
                for (int r = 0; r < 4; ++r) {
                    int row = row0 + r;
                    int nn = row / span, i = row - nn * span;
                    size_t oidx = (size_t)nn * 1152 + ooff + (size_t)col * span + i;
                    outf[oidx] = acc[m][n][r] * scale + fii[oidx];
                }
            }
        }
    }
}

// ---------------------------------------------------------------------------
// TP kernel: thread=(n,u). phase 0: invariants bf16 [Nc][1408];
// phase 1: apply gate gp (bf16), write grouped i-major tpg (bf16).
// ---------------------------------------------------------------------------
__global__ __launch_bounds__(256) void tp_kernel(
    const bf16* __restrict__ xl, const bf16* __restrict__ xr,
    const float* __restrict__ tp_w, const bf16* __restrict__ gp,
    bf16* __restrict__ inv_tp,
    bf16* __restrict__ tpg0, bf16* __restrict__ tpg1, bf16* __restrict__ tpg2,
    W3JPack w3j, int phase, int Nc)
{
    int idx = blockIdx.x * 256 + threadIdx.x;
    int n = idx >> 7, u = idx & 127;
    const size_t O1 = (size_t)Nc * 128, O2 = (size_t)Nc * 512;
    float XL[3][5], XR[3][5];
    XL[0][0] = __bfloat162float(xl[(size_t)n * 128 + u]);
    XR[0][0] = __bfloat162float(xr[(size_t)n * 128 + u]);
    #pragma unroll
    for (int i = 0; i < 3; ++i) {
        XL[1][i] = __bfloat162float(xl[O1 + ((size_t)n * 3 + i) * 128 + u]);
        XR[1][i] = __bfloat162float(xr[O1 + ((size_t)n * 3 + i) * 128 + u]);
    }
    #pragma unroll
    for (int i = 0; i < 5; ++i) {
        XL[2][i] = __bfloat162float(xl[O2 + ((size_t)n * 5 + i) * 128 + u]);
        XR[2][i] = __bfloat162float(xr[O2 + ((size_t)n * 5 + i) * 128 + u]);
    }
    const float SQF[3] = {1.f, 1.7320508075688772f, 2.2360679774997896f};
    #pragma unroll
    for (int p = 0; p < 11; ++p) {
        const int l1 = P_L1[p], l2 = P_L2[p], lo = P_LO[p];
        const int d1 = 2*l1+1, d2 = 2*l2+1, dd = 2*lo+1;
        const float* W = &w3j.v[P_OFF[p]];
        float tw = tp_w[p * 128 + u] * SQF[lo];
        float o[5];
        #pragma unroll
        for (int k = 0; k < dd; ++k) {
            float a = 0.f;
            #pragma unroll
            for (int i = 0; i < d1; ++i)
                #pragma unroll
                for (int jj = 0; jj < d2; ++jj)
                    a += W[(i * d2 + jj) * dd + k] * XL[l1][i] * XR[l2][jj];
            o[k] = a * tw;
        }
        if (phase == 0) {
            float iv;
            if (lo == 0) iv = o[0];
            else {
                float s = 0.f;
                #pragma unroll
                for (int k = 0; k < dd; ++k) s += o[k] * o[k];
                iv = sqrtf(s);
            }
            inv_tp[(size_t)n * 1408 + p * 128 + u] = __float2bfloat16(iv);
        } else {
            float g = __bfloat162float(gp[(size_t)n * 1408 + p * 128 + u]);
            int gg = P_G[p];
            if (lo == 0) {
                tpg0[(size_t)n * 384 + gg * 128 + u] = __float2bfloat16(o[0] * g);
            } else if (lo == 1) {
                #pragma unroll
                for (int k = 0; k < 3; ++k)
                    tpg1[((size_t)n * 3 + k) * 512 + gg * 128 + u] = __float2bfloat16(o[k] * g);
            } else {
                #pragma unroll
                for (int k = 0; k < 5; ++k)
                    tpg2[((size_t)n * 5 + k) * 512 + gg * 128 + u] = __float2bfloat16(o[k] * g);
            }
        }
    }
}

// ---------------------------------------------------------------------------
// Host: real-basis Wigner 3j (exact port of the reference math)
// ---------------------------------------------------------------------------
static double factd(int n) {
    static const double F[10] = {1,1,2,6,24,120,720,5040,40320,362880};
    return F[n];
}

static double su2_cg(int j1,int m1,int j2,int m2,int j3,int m3){
    if (m3 != m1 + m2) return 0.0;
    int vmin = std::max(std::max(-j1 + j2 + m3, -j1 + m1), 0);
    int vmax = std::min(std::min(j2 + j3 + m1, j3 - j1 + j2), j3 + m3);
    if (vmax < vmin) return 0.0;
    double c = std::sqrt((2*j3+1) * factd(j3+j1-j2) * factd(j3-j1+j2) * factd(j1+j2-j3)
               * factd(j3+m3) * factd(j3-m3)
               / (factd(j1+j2+j3+1) * factd(j1-m1) * factd(j1+m1) * factd(j2-m2) * factd(j2+m2)));
    double s = 0.0;
    for (int v = vmin; v <= vmax; ++v) {
        double sg = ((v + j2 + m2) & 1) ? -1.0 : 1.0;
        s += sg * factd(j2+j3+m1-v) * factd(j1-m1+v)
             / (factd(v) * factd(j3-j1+j2-v) * factd(j3+m3-v) * factd(v+j1-j2-m3));
    }
    return c * s;
}

typedef std::complex<double> cd;

static void q_matrix(int l, cd* q) {
    int d = 2*l+1;
    for (int i = 0; i < d*d; ++i) q[i] = cd(0,0);
    const double is2 = 1.0 / std::sqrt(2.0);
    for (int m = -l; m < 0; ++m) {
        q[(l+m)*d + (l-m)] = cd(is2, 0);
        q[(l+m)*d + (l+m)] = cd(0, -is2);
    }
    q[l*d + l] = cd(1,0);
    for (int m = 1; m <= l; ++m) {
        double sg = (m & 1) ? -1.0 : 1.0;
        q[(l+m)*d + (l+m)] = cd(sg*is2, 0);
        q[(l+m)*d + (l-m)] = cd(0, sg*is2);
    }
    cd f = (l==0) ? cd(1,0) : (l==1) ? cd(0,-1) : cd(-1,0);
    for (int i = 0; i < d*d; ++i) q[i] *= f;
}

static void compute_w3j(float* out) {
    for (int p = 0; p < 11; ++p) {
        int l1 = P_L1[p], l2 = P_L2[p], l3 = P_LO[p];
        int d1 = 2*l1+1, d2 = 2*l2+1, d3 = 2*l3+1;
        cd q1[25], q2[25], q3[25];
        q_matrix(l1, q1); q_matrix(l2, q2); q_matrix(l3, q3);
        double nrm = std::sqrt((double)d3);
        for (int a = 0; a < d1; ++a)
        for (int b = 0; b < d2; ++b)
        for (int c = 0; c < d3; ++c) {
            cd s(0,0);
            for (int i = 0; i < d1; ++i)
            for (int k = 0; k < d2; ++k)
            for (int m = 0; m < d3; ++m) {
                double cg = su2_cg(l1, i-l1, l2, k-l2, l3, m-l3);
                if (cg == 0.0) continue;
                s += q1[i*d1 + a] * q2[k*d2 + b] * std::conj(q3[m*d3 + c]) * cg;
            }
            out[P_OFF[p] + (a*d2 + b)*d3 + c] = (float)(s.real() / nrm);
        }
    }
}

// ---------------------------------------------------------------------------
extern "C" void kernel_launch(void* const* d_in, const int* in_sizes, int n_in,
                              void* d_out, int out_size, void* d_ws, size_t ws_size,
                              hipStream_t stream)
{
    (void)in_sizes; (void)n_in; (void)out_size;
    const float* x    = (const float*)d_in[0];
    const float* fii  = (const float*)d_in[1];
    const float* Wg_l = (const float*)d_in[2];
    const float* bg_l = (const float*)d_in[3];
    const float* Wl0  = (const float*)d_in[4];
    const float* Wl1  = (const float*)d_in[5];
    const float* Wl2  = (const float*)d_in[6];
    const float* bl0  = (const float*)d_in[7];
    const float* Wg_r = (const float*)d_in[8];
    const float* bg_r = (const float*)d_in[9];
    const float* Wr0  = (const float*)d_in[10];
    const float* Wr1  = (const float*)d_in[11];
    const float* Wr2  = (const float*)d_in[12];
    const float* br0  = (const float*)d_in[13];
    const float* tp_w = (const float*)d_in[14];
    const float* Wg_p = (const float*)d_in[15];
    const float* bg_p = (const float*)d_in[16];
    const float* Wp0  = (const float*)d_in[17];
    const float* Wp1  = (const float*)d_in[18];
    const float* Wp2  = (const float*)d_in[19];
    float* out = (float*)d_out;

    W3JPack w3j;
    compute_w3j(w3j.v);

    auto al = [](size_t b) { return (b + 255) & ~(size_t)255; };
    char* base = (char*)d_ws;
    size_t woff = 0;
    auto walloc = [&](size_t elems) { void* p = base + woff; woff += al(elems * 2); return (bf16*)p; };
    bf16* tWg   = walloc((size_t)768 * 384);      // [Wg_l | Wg_r] transposed
    bf16* tWl0  = walloc(128 * 128);
    bf16* tWl1  = walloc(128 * 128);
    bf16* tWl2  = walloc(128 * 128);
    bf16* tWr0  = walloc(128 * 128);
    bf16* tWr1  = walloc(128 * 128);
    bf16* tWr2  = walloc(128 * 128);
    bf16* tWg_p = walloc((size_t)1408 * 1408);
    bf16* tWp0  = walloc(128 * 384);
    bf16* tWp1  = walloc(128 * 512);
    bf16* tWp2  = walloc(128 * 512);
    const size_t wtotal = woff;

    // per-node bytes: xl 2304 + xr 2304 + R3 11776 = 16384
    int c = 1; size_t Nc;
    for (;; c *= 2) {
        Nc = NN / c;
        size_t tot = wtotal + 2 * al(Nc * 2304) + al(Nc * 11776);
        if (tot <= ws_size || c >= 32) break;
    }
    char* cb = base + wtotal;
    bf16* xl = (bf16*)cb;  cb += al(Nc * 2304);
    bf16* xr = (bf16*)cb;  cb += al(Nc * 2304);
    char* R3 = cb;
    // t1
    bf16* inv_x = (bf16*)R3;                    // [0, 768Nc)
    bf16* gbuf  = (bf16*)(R3 + Nc * 768);       // [768Nc, 2304Nc)  [Nc][768]
    bf16* xg_l  = (bf16*)(R3 + Nc * 2304);      // [2304Nc, 4608Nc)
    bf16* xg_r  = (bf16*)(R3 + Nc * 4608);      // [4608Nc, 6912Nc)
    // t2/t3
    bf16* inv_tp = (bf16*)R3;                   // [0, 2816Nc)
    bf16* tpg0   = (bf16*)R3;                   // [0, 768Nc)
    bf16* tpg1   = (bf16*)(R3 + Nc * 768);      // [768Nc, 3840Nc)
    bf16* tpg2   = (bf16*)(R3 + Nc * 3840);     // [3840Nc, 8960Nc)
    bf16* gp     = (bf16*)(R3 + Nc * 8960);     // [8960Nc, 11776Nc)

    const float s128 = 0.08838834764831845f;   // 1/sqrt(128)
    const float s384 = 0.05103103630798287f;   // 1/sqrt(384)
    const float s512 = 0.044194173824159216f;  // 1/sqrt(512)
    dim3 blk(256);

    // batched weight convert+transpose (once)
    WPack wp;
    wp.W[0] = Wg_l; wp.Bt[0] = tWg;             wp.K[0] = 384;  wp.Nn[0] = 384;
    wp.W[1] = Wg_r; wp.Bt[1] = tWg + 384*384;   wp.K[1] = 384;  wp.Nn[1] = 384;
    wp.W[2] = Wl0;  wp.Bt[2] = tWl0;            wp.K[2] = 128;  wp.Nn[2] = 128;
    wp.W[3] = Wl1;  wp.Bt[3] = tWl1;            wp.K[3] = 128;  wp.Nn[3] = 128;
    wp.W[4] = Wl2;  wp.Bt[4] = tWl2;            wp.K[4] = 128;  wp.Nn[4] = 128;
    wp.W[5] = Wr0;  wp.Bt[5] = tWr0;            wp.K[5] = 128;  wp.Nn[5] = 128;
    wp.W[6] = Wr1;  wp.Bt[6] = tWr1;            wp.K[6] = 128;  wp.Nn[6] = 128;
    wp.W[7] = Wr2;  wp.Bt[7] = tWr2;            wp.K[7] = 128;  wp.Nn[7] = 128;
    wp.W[8] = Wg_p; wp.Bt[8] = tWg_p;           wp.K[8] = 1408; wp.Nn[8] = 1408;
    wp.W[9] = Wp0;  wp.Bt[9] = tWp0;            wp.K[9] = 384;  wp.Nn[9] = 128;
    wp.W[10]= Wp1;  wp.Bt[10]= tWp1;            wp.K[10]= 512;  wp.Nn[10]= 128;
    wp.W[11]= Wp2;  wp.Bt[11]= tWp2;            wp.K[11]= 512;  wp.Nn[11]= 128;
    wconv_all<<<dim3(44, 44, 12), blk, 0, stream>>>(wp);

    const int gy = (int)(Nc / 128);
    for (int ch = 0; ch < c; ++ch) {
        const float* xc = x   + (size_t)ch * Nc * 1152;
        const float* fc = fii + (size_t)ch * Nc * 1152;
        float*       oc = out + (size_t)ch * Nc * 1152;

        invx_kernel<<<dim3((int)(Nc * 384 / 256)), blk, 0, stream>>>(xc, inv_x);

        // K2 fused l+r: gbuf = silu(inv_x @ [Wg_l|Wg_r] + [bg_l|bg_r])
        mgemm<<<dim3(6, gy), blk, 0, stream>>>(inv_x, tWg, bg_l, bg_r, 384,
                                               gbuf, 768, 384);

        // gated-x for both sides
        gate_apply2<<<dim3((int)(Nc / 2)), blk, 0, stream>>>(xc, gbuf, xg_l, xg_r, (int)Nc);

        // K3 batched: 6 segments (l0/l1/l2 x l/r), all N=128 K=128
        {
            SegPack sp{};
            const bf16* As[6]  = {xg_l, xg_l + Nc*128, xg_l + Nc*512,
                                  xg_r, xg_r + Nc*128, xg_r + Nc*512};
            const bf16* Bs[6]  = {tWl0, tWl1, tWl2, tWr0, tWr1, tWr2};
            const float* bi[6] = {bl0, nullptr, nullptr, br0, nullptr, nullptr};
            bf16* os[6]        = {xl, xl + Nc*128, xl + Nc*512,
                                  xr, xr + Nc*128, xr + Nc*512};
            int rows[6] = {gy, 3*gy, 5*gy, gy, 3*gy, 5*gy};
            int acc_r = 0;
            for (int s = 0; s < 6; ++s) {
                sp.A[s] = As[s]; sp.Bt[s] = Bs[s]; sp.bias[s] = bi[s]; sp.out[s] = os[s];
                sp.scale[s] = s128; sp.K[s] = 128;
                acc_r += rows[s]; sp.segEnd[s] = acc_r;
                sp.ooff[s] = 0; sp.span[s] = 1;
            }
            mgemm_seg<1><<<dim3(1, 18*gy), blk, 0, stream>>>(sp, nullptr, nullptr);
        }

        // TP invariants
        tp_kernel<<<dim3((int)(Nc / 2)), blk, 0, stream>>>(xl, xr, tp_w, gp, inv_tp,
            tpg0, tpg1, tpg2, w3j, 0, (int)Nc);

        // K5: gp = silu(inv_tp @ Wg_p + bg_p)  (bf16 out)
        mgemm<<<dim3(11, gy), blk, 0, stream>>>(inv_tp, tWg_p, bg_p, nullptr, 1408,
                                                gp, 1408, 1408);

        // TP recompute + gate apply
        tp_kernel<<<dim3((int)(Nc / 2)), blk, 0, stream>>>(xl, xr, tp_w, gp, inv_tp,
            tpg0, tpg1, tpg2, w3j, 1, (int)Nc);

        // K6 batched: 3 segments -> out (+fii), e3nn layout
        {
            SegPack sp{};
            sp.A[0] = tpg0; sp.Bt[0] = tWp0; sp.K[0] = 384; sp.scale[0] = s384;
            sp.segEnd[0] = gy;      sp.ooff[0] = 0;   sp.span[0] = 1;
            sp.A[1] = tpg1; sp.Bt[1] = tWp1; sp.K[1] = 512; sp.scale[1] = s512;
            sp.segEnd[1] = 4*gy;    sp.ooff[1] = 128; sp.span[1] = 3;
            sp.A[2] = tpg2; sp.Bt[2] = tWp2; sp.K[2] = 512; sp.scale[2] = s512;
            sp.segEnd[2] = 9*gy;    sp.ooff[2] = 512; sp.span[2] = 5;
            for (int s = 3; s < 6; ++s) sp.segEnd[s] = 9*gy + 1 + s; // unreachable
            mgemm_seg<2><<<dim3(1, 9*gy), blk, 0, stream>>>(sp, fc, oc);
        }
    }
}